// Round 1
// baseline (1543.887 us; speedup 1.0000x reference)
//
#include <hip/hip_runtime.h>
#include <hip/hip_bf16.h>

// ---------------------------------------------------------------------------
// Longformer-style forward: B=2, S=4096, HID=768, L=4, H=12, D=64, W=128
// bf16 MFMA GEMMs (m97 pattern), MFMA band attention, fp32 LN/residual spine.
// ---------------------------------------------------------------------------

typedef __bf16 bf16;
typedef bf16  bf16x8  __attribute__((ext_vector_type(8)));
typedef float floatx4 __attribute__((ext_vector_type(4)));

#define MFMA16(a, b, c) __builtin_amdgcn_mfma_f32_16x16x32_bf16((a), (b), (c), 0, 0, 0)

__device__ __forceinline__ void gld_lds16(const bf16* gp, bf16* lp) {
  // async global->LDS, 16B per lane; LDS dest = wave-uniform base + lane*16
  __builtin_amdgcn_global_load_lds(
      (const __attribute__((address_space(1))) void*)gp,
      (__attribute__((address_space(3))) void*)lp, 16, 0, 0);
}

// ------------------------- workspace layout (bytes) ------------------------
static constexpr size_t SZ_WTQKV = (size_t)4 * 2304 * 768 * 2;
static constexpr size_t SZ_WTO   = (size_t)4 * 768 * 768 * 2;
static constexpr size_t SZ_WTI   = (size_t)4 * 3072 * 768 * 2;
static constexpr size_t SZ_WTF   = (size_t)4 * 768 * 3072 * 2;
static constexpr size_t SZ_BQKV  = (size_t)4 * 2304 * 4;
static constexpr size_t SZ_H32   = (size_t)8192 * 768 * 4;
static constexpr size_t SZ_HBF   = (size_t)8192 * 768 * 2;
static constexpr size_t SZ_QKV   = (size_t)8192 * 2304 * 2;
static constexpr size_t SZ_ATTN  = (size_t)8192 * 768 * 2;
static constexpr size_t SZ_TMP   = (size_t)8192 * 768 * 4;

static constexpr size_t OFF_WTQKV = 0;
static constexpr size_t OFF_WTO   = OFF_WTQKV + SZ_WTQKV;
static constexpr size_t OFF_WTI   = OFF_WTO   + SZ_WTO;
static constexpr size_t OFF_WTF   = OFF_WTI   + SZ_WTI;
static constexpr size_t OFF_BQKV  = OFF_WTF   + SZ_WTF;
static constexpr size_t OFF_H32   = OFF_BQKV  + SZ_BQKV;
static constexpr size_t OFF_HBF   = OFF_H32   + SZ_H32;
static constexpr size_t OFF_QKV   = OFF_HBF   + SZ_HBF;
static constexpr size_t OFF_ATTN  = OFF_QKV   + SZ_QKV;
static constexpr size_t OFF_TMP   = OFF_ATTN  + SZ_ATTN;
static constexpr size_t OFF_FFN1  = OFF_TMP   + SZ_TMP;

// ------------------------- weight transpose + cast -------------------------
// src: fp32 [K][N] (per layer), dst: bf16 [N][K] (per layer)
__global__ __launch_bounds__(256) void transpose_cast(
    const float* __restrict__ src, bf16* __restrict__ dst,
    int K, int N, long sStride, long dStride) {
  __shared__ float tile[32][33];
  const int l = blockIdx.z;
  src += (long)l * sStride;
  dst += (long)l * dStride;
  const int n0 = blockIdx.x * 32, k0 = blockIdx.y * 32;
  const int tx = threadIdx.x, ty = threadIdx.y; // (32,8)
#pragma unroll
  for (int i = 0; i < 4; ++i)
    tile[ty + i * 8][tx] = src[(long)(k0 + ty + i * 8) * N + n0 + tx];
  __syncthreads();
#pragma unroll
  for (int i = 0; i < 4; ++i)
    dst[(long)(n0 + ty + i * 8) * K + k0 + tx] = (bf16)tile[tx][ty + i * 8];
}

__global__ void bias_concat(const float* __restrict__ bq, const float* __restrict__ bk,
                            const float* __restrict__ bv, float* __restrict__ bqkv) {
  int i = blockIdx.x * 256 + threadIdx.x; // 4*2304
  if (i >= 4 * 2304) return;
  int l = i / 2304, p = i % 2304;
  float v = (p < 768) ? bq[l * 768 + p]
          : (p < 1536) ? bk[l * 768 + p - 768] : bv[l * 768 + p - 1536];
  bqkv[i] = v;
}

// ------------------------------ LN helpers ---------------------------------
__device__ __forceinline__ void block_stats(float s1, float s2, float* red,
                                            float& mean, float& inv) {
  const int lane = threadIdx.x & 63, wave = threadIdx.x >> 6;
#pragma unroll
  for (int off = 32; off > 0; off >>= 1) {
    s1 += __shfl_down(s1, off, 64);
    s2 += __shfl_down(s2, off, 64);
  }
  if (lane == 0) { red[wave] = s1; red[4 + wave] = s2; }
  __syncthreads();
  s1 = red[0] + red[1] + red[2] + red[3];
  s2 = red[4] + red[5] + red[6] + red[7];
  mean = s1 * (1.f / 768.f);
  float var = s2 * (1.f / 768.f) - mean * mean;
  inv = rsqrtf(var + 1e-12f);
}

__global__ __launch_bounds__(256) void embed_ln_kernel(
    const float* __restrict__ emb, const float* __restrict__ pos,
    const float* __restrict__ tok, const float* __restrict__ g,
    const float* __restrict__ bta, float* __restrict__ h32, bf16* __restrict__ hbf) {
  __shared__ float red[8];
  const long base = (long)blockIdx.x * 768;
  const int s = blockIdx.x & 4095;
  const int t = threadIdx.x;
  float x[3], s1 = 0.f, s2 = 0.f;
#pragma unroll
  for (int i = 0; i < 3; ++i) {
    int c = t + i * 256;
    float v = emb[base + c] + pos[(long)(s + 1) * 768 + c] + tok[c];
    x[i] = v; s1 += v; s2 += v * v;
  }
  float mean, inv;
  block_stats(s1, s2, red, mean, inv);
#pragma unroll
  for (int i = 0; i < 3; ++i) {
    int c = t + i * 256;
    float y = (x[i] - mean) * inv * g[c] + bta[c];
    h32[base + c] = y;
    hbf[base + c] = (bf16)y;
  }
}

__global__ __launch_bounds__(256) void add_ln_kernel(
    float* __restrict__ h32, const float* __restrict__ tmp,
    const float* __restrict__ g, const float* __restrict__ bta, bf16* __restrict__ hbf) {
  __shared__ float red[8];
  const long base = (long)blockIdx.x * 768;
  const int t = threadIdx.x;
  float x[3], s1 = 0.f, s2 = 0.f;
#pragma unroll
  for (int i = 0; i < 3; ++i) {
    int c = t + i * 256;
    float v = h32[base + c] + tmp[base + c];
    x[i] = v; s1 += v; s2 += v * v;
  }
  float mean, inv;
  block_stats(s1, s2, red, mean, inv);
#pragma unroll
  for (int i = 0; i < 3; ++i) {
    int c = t + i * 256;
    float y = (x[i] - mean) * inv * g[c] + bta[c];
    h32[base + c] = y;
    hbf[base + c] = (bf16)y;
  }
}

// ------------------------------- GEMM --------------------------------------
// C[M,N] = A[M,K] @ W[K,N] + bias, with BT = W^T as bf16 [N][K].
// 128x128 tile, BK=64, 4 waves each 64x64, global_load_lds staging.
// MODE: 0 = fp32 store, 1 = bf16 store, 2 = bf16 store + exact GELU
template <int MODE>
__global__ __launch_bounds__(256) void gemm_kernel(
    const bf16* __restrict__ A, const bf16* __restrict__ BT,
    const float* __restrict__ bias, void* __restrict__ Cout, int N, int K) {
  __shared__ bf16 As[128 * 64];
  __shared__ bf16 Bs[128 * 64];
  const int tid  = threadIdx.x;
  const int wave = tid >> 6, lane = tid & 63, l15 = lane & 15, quad = lane >> 4;
  const int wm = wave >> 1, wn = wave & 1;
  const long m0 = (long)blockIdx.y * 128;
  const int  n0 = blockIdx.x * 128;

  floatx4 acc[4][4] = {};
  const bf16* Ag = A + m0 * K;
  const bf16* Bg = BT + (long)n0 * K;
  const int rowoff = tid >> 3, sc = tid & 7;

  for (int kt = 0; kt < K; kt += 64) {
#pragma unroll
    for (int p = 0; p < 4; ++p) {
      const int row = p * 32 + rowoff;
      gld_lds16(Ag + (long)row * K + kt + sc * 8, &As[p * 2048 + wave * 512]);
      gld_lds16(Bg + (long)row * K + kt + sc * 8, &Bs[p * 2048 + wave * 512]);
    }
    __syncthreads();
#pragma unroll
    for (int kk = 0; kk < 2; ++kk) {
      const int ko = kk * 32 + quad * 8;
      bf16x8 af[4], bfr[4];
#pragma unroll
      for (int mt = 0; mt < 4; ++mt)
        af[mt] = *(const bf16x8*)&As[(wm * 64 + mt * 16 + l15) * 64 + ko];
#pragma unroll
      for (int nt = 0; nt < 4; ++nt)
        bfr[nt] = *(const bf16x8*)&Bs[(wn * 64 + nt * 16 + l15) * 64 + ko];
#pragma unroll
      for (int mt = 0; mt < 4; ++mt)
#pragma unroll
        for (int nt = 0; nt < 4; ++nt)
          acc[mt][nt] = MFMA16(af[mt], bfr[nt], acc[mt][nt]);
    }
    __syncthreads();
  }

#pragma unroll
  for (int nt = 0; nt < 4; ++nt) {
    const int col = n0 + wn * 64 + nt * 16 + l15;
    const float bb = bias[col];
#pragma unroll
    for (int mt = 0; mt < 4; ++mt) {
      const long row = m0 + wm * 64 + mt * 16 + quad * 4;
#pragma unroll
      for (int r = 0; r < 4; ++r) {
        float v = acc[mt][nt][r] + bb;
        if (MODE == 2) v = 0.5f * v * (1.f + erff(v * 0.70710678118654752f));
        if (MODE == 0) ((float*)Cout)[(row + r) * N + col] = v;
        else           ((bf16*)Cout)[(row + r) * N + col] = (bf16)v;
      }
    }
  }
}

// ----------------------------- attention -----------------------------------
// One block = (batch b, head h, 64-query chunk). Window = [q0-128, q0+192).
// Phase A: QK^T via MFMA over five 64-key tiles -> masked scores to LDS (bf16)
// Phase B: per-row softmax (rows are wave-private; 16-lane shuffle reductions)
// Phase C: P @ V via MFMA with V^T tiles -> bf16 merged-heads output
__global__ __launch_bounds__(256) void attn_kernel(
    const bf16* __restrict__ qkv, const int* __restrict__ amask,
    bf16* __restrict__ attn_out) {
  constexpr int S = 4096, HID3 = 2304;
  __shared__ bf16 Ss[64 * 328]; // scores -> probs, rows padded to 328
  __shared__ bf16 Ts[64 * 72];  // K tile [key][72] or V^T tile [d][72]

  const int q0 = blockIdx.x * 64, h = blockIdx.y, b = blockIdx.z;
  const int tid = threadIdx.x, wave = tid >> 6, lane = tid & 63;
  const int l15 = lane & 15, quad = lane >> 4;

  const bf16* Qb = qkv + (long)b * S * HID3 + h * 64;
  const bf16* Kb = Qb + 768;
  const bf16* Vb = Qb + 1536;

  bf16x8 qf[2];
  {
    const long qrow = q0 + wave * 16 + l15;
    qf[0] = *(const bf16x8*)&Qb[qrow * HID3 + quad * 8];
    qf[1] = *(const bf16x8*)&Qb[qrow * HID3 + 32 + quad * 8];
  }

  float mrow[4] = {-3e38f, -3e38f, -3e38f, -3e38f};

  // ---- Phase A: scores ----
  for (int t = 0; t < 5; ++t) {
    const int j0 = q0 - 128 + t * 64;
    __syncthreads();
    for (int i = tid; i < 512; i += 256) {
      const int key = i >> 3, sc2 = i & 7, j = j0 + key;
      uint4 val = make_uint4(0u, 0u, 0u, 0u);
      if (j >= 0 && j < S) val = *(const uint4*)&Kb[(long)j * HID3 + sc2 * 8];
      *(uint4*)&Ts[key * 72 + sc2 * 8] = val;
    }
    __syncthreads();
    floatx4 sacc[4] = {};
#pragma unroll
    for (int kk = 0; kk < 2; ++kk) {
      const int ko = kk * 32 + quad * 8;
#pragma unroll
      for (int nt = 0; nt < 4; ++nt) {
        bf16x8 kf = *(const bf16x8*)&Ts[(nt * 16 + l15) * 72 + ko];
        sacc[nt] = MFMA16(qf[kk], kf, sacc[nt]);
      }
    }
#pragma unroll
    for (int nt = 0; nt < 4; ++nt) {
      const int jj = t * 64 + nt * 16 + l15;
      const int j = j0 + nt * 16 + l15;
      bool jv = (j >= 0) && (j < S);
      if (jv) jv = (amask[b * S + j] != 0);
#pragma unroll
      for (int r = 0; r < 4; ++r) {
        const int qi = wave * 16 + quad * 4 + r;
        const bool ok = jv && (jj >= qi) && (jj <= qi + 256);
        const float sv = ok ? sacc[nt][r] * 0.125f : -1e9f;
        mrow[r] = fmaxf(mrow[r], sv);
        Ss[(wave * 16 + quad * 4 + r) * 328 + jj] = (bf16)sv;
      }
    }
  }
#pragma unroll
  for (int off = 1; off < 16; off <<= 1)
#pragma unroll
    for (int r = 0; r < 4; ++r)
      mrow[r] = fmaxf(mrow[r], __shfl_xor(mrow[r], off, 64));

  __syncthreads();

  // ---- Phase B: softmax (unnormalized probs; scale at PV epilogue) ----
  float ssum[4] = {0.f, 0.f, 0.f, 0.f};
  for (int i = 0; i < 20; ++i) {
#pragma unroll
    for (int r = 0; r < 4; ++r) {
      const int idx = (wave * 16 + quad * 4 + r) * 328 + i * 16 + l15;
      const float sv = (float)Ss[idx];
      const float p = __expf(sv - mrow[r]);
      ssum[r] += p;
      Ss[idx] = (bf16)p;
    }
  }
#pragma unroll
  for (int off = 1; off < 16; off <<= 1)
#pragma unroll
    for (int r = 0; r < 4; ++r) ssum[r] += __shfl_xor(ssum[r], off, 64);
  float inv[4];
#pragma unroll
  for (int r = 0; r < 4; ++r) inv[r] = 1.f / ssum[r];

  // ---- Phase C: P @ V ----
  floatx4 oacc[4] = {};
  for (int t = 0; t < 5; ++t) {
    const int j0 = q0 - 128 + t * 64;
    __syncthreads();
    for (int i = tid; i < 512; i += 256) {
      const int key = i >> 3, ds = i & 7, j = j0 + key;
      if (j >= 0 && j < S) {
        bf16x8 v = *(const bf16x8*)&Vb[(long)j * HID3 + ds * 8];
#pragma unroll
        for (int u = 0; u < 8; ++u) Ts[(ds * 8 + u) * 72 + key] = v[u];
      } else {
#pragma unroll
        for (int u = 0; u < 8; ++u) Ts[(ds * 8 + u) * 72 + key] = (bf16)0.f;
      }
    }
    __syncthreads();
#pragma unroll
    for (int kk = 0; kk < 2; ++kk) {
      const int ko = kk * 32 + quad * 8;
      bf16x8 pf = *(const bf16x8*)&Ss[(wave * 16 + l15) * 328 + t * 64 + ko];
#pragma unroll
      for (int nt = 0; nt < 4; ++nt) {
        bf16x8 vf = *(const bf16x8*)&Ts[(nt * 16 + l15) * 72 + ko];
        oacc[nt] = MFMA16(pf, vf, oacc[nt]);
      }
    }
  }

  const long orow = (long)b * S + q0 + wave * 16 + quad * 4;
#pragma unroll
  for (int nt = 0; nt < 4; ++nt)
#pragma unroll
    for (int r = 0; r < 4; ++r)
      attn_out[(orow + r) * 768 + h * 64 + nt * 16 + l15] =
          (bf16)(oacc[nt][r] * inv[r]);
}

// ------------------------------ final head ---------------------------------
__global__ __launch_bounds__(256) void final_kernel(
    const float* __restrict__ h32, const float* __restrict__ Wp,
    const float* __restrict__ bp, float* __restrict__ out) {
  const int wave = threadIdx.x >> 6, lane = threadIdx.x & 63;
  const long tok = (long)blockIdx.x * 4 + wave;
  float s = 0.f;
#pragma unroll
  for (int i = 0; i < 12; ++i) {
    const int c = lane + i * 64;
    s += h32[tok * 768 + c] * Wp[c];
  }
#pragma unroll
  for (int off = 32; off > 0; off >>= 1) s += __shfl_down(s, off, 64);
  if (lane == 0) out[tok] = 1.f / (1.f + __expf(-(s + bp[0])));
}

// ------------------------------ launcher -----------------------------------
extern "C" void kernel_launch(void* const* d_in, const int* in_sizes, int n_in,
                              void* d_out, int out_size, void* d_ws, size_t ws_size,
                              hipStream_t stream) {
  const float* emb   = (const float*)d_in[0];
  const int*   amask = (const int*)d_in[1];
  const float* pos   = (const float*)d_in[2];
  const float* tok   = (const float*)d_in[3];
  const float* elng  = (const float*)d_in[4];
  const float* elnb  = (const float*)d_in[5];
  const float* Wq = (const float*)d_in[6];   const float* bq = (const float*)d_in[7];
  const float* Wk = (const float*)d_in[8];   const float* bk = (const float*)d_in[9];
  const float* Wv = (const float*)d_in[10];  const float* bv = (const float*)d_in[11];
  const float* Wo = (const float*)d_in[12];  const float* bo = (const float*)d_in[13];
  const float* ln1g = (const float*)d_in[14]; const float* ln1b = (const float*)d_in[15];
  const float* Wi = (const float*)d_in[16];  const float* bi = (const float*)d_in[17];
  const float* Wf = (const float*)d_in[18];  const float* bfb = (const float*)d_in[19];
  const float* ln2g = (const float*)d_in[20]; const float* ln2b = (const float*)d_in[21];
  const float* Wp = (const float*)d_in[22];  const float* bp = (const float*)d_in[23];
  float* out = (float*)d_out;

  char* ws = (char*)d_ws;
  bf16*  WTqkv = (bf16*)(ws + OFF_WTQKV);
  bf16*  WTo   = (bf16*)(ws + OFF_WTO);
  bf16*  WTi   = (bf16*)(ws + OFF_WTI);
  bf16*  WTf   = (bf16*)(ws + OFF_WTF);
  float* bqkv  = (float*)(ws + OFF_BQKV);
  float* h32   = (float*)(ws + OFF_H32);
  bf16*  hbf   = (bf16*)(ws + OFF_HBF);
  bf16*  qkvb  = (bf16*)(ws + OFF_QKV);
  bf16*  attnb = (bf16*)(ws + OFF_ATTN);
  float* tmp   = (float*)(ws + OFF_TMP);
  bf16*  ffn1  = (bf16*)(ws + OFF_FFN1);

  const dim3 tb(32, 8, 1);
  transpose_cast<<<dim3(24, 24, 4), tb, 0, stream>>>(Wq, WTqkv,               768, 768,  (long)768 * 768,  (long)2304 * 768);
  transpose_cast<<<dim3(24, 24, 4), tb, 0, stream>>>(Wk, WTqkv + 768 * 768,   768, 768,  (long)768 * 768,  (long)2304 * 768);
  transpose_cast<<<dim3(24, 24, 4), tb, 0, stream>>>(Wv, WTqkv + 1536 * 768,  768, 768,  (long)768 * 768,  (long)2304 * 768);
  transpose_cast<<<dim3(24, 24, 4), tb, 0, stream>>>(Wo, WTo,                 768, 768,  (long)768 * 768,  (long)768 * 768);
  transpose_cast<<<dim3(96, 24, 4), tb, 0, stream>>>(Wi, WTi,                 768, 3072, (long)768 * 3072, (long)3072 * 768);
  transpose_cast<<<dim3(24, 96, 4), tb, 0, stream>>>(Wf, WTf,                 3072, 768, (long)3072 * 768, (long)768 * 3072);
  bias_concat<<<36, 256, 0, stream>>>(bq, bk, bv, bqkv);

  embed_ln_kernel<<<8192, 256, 0, stream>>>(emb, pos, tok, elng, elnb, h32, hbf);

  for (int l = 0; l < 4; ++l) {
    gemm_kernel<1><<<dim3(18, 64), 256, 0, stream>>>(
        hbf, WTqkv + (size_t)l * 2304 * 768, bqkv + l * 2304, qkvb, 2304, 768);
    attn_kernel<<<dim3(64, 12, 2), 256, 0, stream>>>(qkvb, amask, attnb);
    gemm_kernel<0><<<dim3(6, 64), 256, 0, stream>>>(
        attnb, WTo + (size_t)l * 768 * 768, bo + l * 768, tmp, 768, 768);
    add_ln_kernel<<<8192, 256, 0, stream>>>(h32, tmp, ln1g + l * 768, ln1b + l * 768, hbf);
    gemm_kernel<2><<<dim3(24, 64), 256, 0, stream>>>(
        hbf, WTi + (size_t)l * 3072 * 768, bi + l * 3072, ffn1, 3072, 768);
    gemm_kernel<0><<<dim3(6, 64), 256, 0, stream>>>(
        ffn1, WTf + (size_t)l * 768 * 3072, bfb + l * 768, tmp, 768, 3072);
    add_ln_kernel<<<8192, 256, 0, stream>>>(h32, tmp, ln2g + l * 768, ln2b + l * 768, hbf);
  }

  final_kernel<<<2048, 256, 0, stream>>>(h32, Wp, bp, out);
}

// Round 2
// 1542.603 us; speedup vs baseline: 1.0008x; 1.0008x over previous
//
#include <hip/hip_runtime.h>
#include <hip/hip_bf16.h>

// ---------------------------------------------------------------------------
// Longformer-style forward: B=2, S=4096, HID=768, L=4, H=12, D=64, W=128
// bf16 MFMA GEMMs (m97 pattern), MFMA band attention, fp32 LN/residual spine.
// R2: tanh-GELU epilogue (erf was ~half of FFN1 VALU time), split-K=2 for the
//     N=768 GEMMs (O-proj, FFN2) with reduction fused into add_ln.
// ---------------------------------------------------------------------------

typedef __bf16 bf16;
typedef bf16  bf16x8  __attribute__((ext_vector_type(8)));
typedef float floatx4 __attribute__((ext_vector_type(4)));

#define MFMA16(a, b, c) __builtin_amdgcn_mfma_f32_16x16x32_bf16((a), (b), (c), 0, 0, 0)

__device__ __forceinline__ void gld_lds16(const bf16* gp, bf16* lp) {
  __builtin_amdgcn_global_load_lds(
      (const __attribute__((address_space(1))) void*)gp,
      (__attribute__((address_space(3))) void*)lp, 16, 0, 0);
}

__device__ __forceinline__ float gelu_tanh(float v) {
  // 0.5*v*(1+tanh(sqrt(2/pi)*(v+0.044715 v^3))); tanh(t)=1-2/(e^{2t}+1)
  float t = 0.7978845608028654f * (v + 0.044715f * v * v * v);
  float e = __expf(2.f * t);
  float th = 1.f - 2.f / (e + 1.f);
  return 0.5f * v * (1.f + th);
}

// ------------------------- workspace layout (bytes) ------------------------
static constexpr size_t SZ_WTQKV = (size_t)4 * 2304 * 768 * 2;
static constexpr size_t SZ_WTO   = (size_t)4 * 768 * 768 * 2;
static constexpr size_t SZ_WTI   = (size_t)4 * 3072 * 768 * 2;
static constexpr size_t SZ_WTF   = (size_t)4 * 768 * 3072 * 2;
static constexpr size_t SZ_BQKV  = (size_t)4 * 2304 * 4;
static constexpr size_t SZ_H32   = (size_t)8192 * 768 * 4;
static constexpr size_t SZ_HBF   = (size_t)8192 * 768 * 2;
static constexpr size_t SZ_QKV   = (size_t)8192 * 2304 * 2;   // >= 25.2MB fp32 overlay
static constexpr size_t SZ_ATTN  = (size_t)8192 * 768 * 2;
static constexpr size_t SZ_TMP   = (size_t)8192 * 768 * 4;

static constexpr size_t OFF_WTQKV = 0;
static constexpr size_t OFF_WTO   = OFF_WTQKV + SZ_WTQKV;
static constexpr size_t OFF_WTI   = OFF_WTO   + SZ_WTO;
static constexpr size_t OFF_WTF   = OFF_WTI   + SZ_WTI;
static constexpr size_t OFF_BQKV  = OFF_WTF   + SZ_WTF;
static constexpr size_t OFF_H32   = OFF_BQKV  + SZ_BQKV;
static constexpr size_t OFF_HBF   = OFF_H32   + SZ_H32;
static constexpr size_t OFF_QKV   = OFF_HBF   + SZ_HBF;
static constexpr size_t OFF_ATTN  = OFF_QKV   + SZ_QKV;
static constexpr size_t OFF_TMP   = OFF_ATTN  + SZ_ATTN;
static constexpr size_t OFF_FFN1  = OFF_TMP   + SZ_TMP;

// ------------------------- weight transpose + cast -------------------------
__global__ __launch_bounds__(256) void transpose_cast(
    const float* __restrict__ src, bf16* __restrict__ dst,
    int K, int N, long sStride, long dStride) {
  __shared__ float tile[32][33];
  const int l = blockIdx.z;
  src += (long)l * sStride;
  dst += (long)l * dStride;
  const int n0 = blockIdx.x * 32, k0 = blockIdx.y * 32;
  const int tx = threadIdx.x, ty = threadIdx.y; // (32,8)
#pragma unroll
  for (int i = 0; i < 4; ++i)
    tile[ty + i * 8][tx] = src[(long)(k0 + ty + i * 8) * N + n0 + tx];
  __syncthreads();
#pragma unroll
  for (int i = 0; i < 4; ++i)
    dst[(long)(n0 + ty + i * 8) * K + k0 + tx] = (bf16)tile[tx][ty + i * 8];
}

__global__ void bias_concat(const float* __restrict__ bq, const float* __restrict__ bk,
                            const float* __restrict__ bv, float* __restrict__ bqkv) {
  int i = blockIdx.x * 256 + threadIdx.x; // 4*2304
  if (i >= 4 * 2304) return;
  int l = i / 2304, p = i % 2304;
  float v = (p < 768) ? bq[l * 768 + p]
          : (p < 1536) ? bk[l * 768 + p - 768] : bv[l * 768 + p - 1536];
  bqkv[i] = v;
}

// ------------------------------ LN helpers ---------------------------------
__device__ __forceinline__ void block_stats(float s1, float s2, float* red,
                                            float& mean, float& inv) {
  const int lane = threadIdx.x & 63, wave = threadIdx.x >> 6;
#pragma unroll
  for (int off = 32; off > 0; off >>= 1) {
    s1 += __shfl_down(s1, off, 64);
    s2 += __shfl_down(s2, off, 64);
  }
  if (lane == 0) { red[wave] = s1; red[4 + wave] = s2; }
  __syncthreads();
  s1 = red[0] + red[1] + red[2] + red[3];
  s2 = red[4] + red[5] + red[6] + red[7];
  mean = s1 * (1.f / 768.f);
  float var = s2 * (1.f / 768.f) - mean * mean;
  inv = rsqrtf(var + 1e-12f);
}

__global__ __launch_bounds__(256) void embed_ln_kernel(
    const float* __restrict__ emb, const float* __restrict__ pos,
    const float* __restrict__ tok, const float* __restrict__ g,
    const float* __restrict__ bta, float* __restrict__ h32, bf16* __restrict__ hbf) {
  __shared__ float red[8];
  const long base = (long)blockIdx.x * 768;
  const int s = blockIdx.x & 4095;
  const int t = threadIdx.x;
  float x[3], s1 = 0.f, s2 = 0.f;
#pragma unroll
  for (int i = 0; i < 3; ++i) {
    int c = t + i * 256;
    float v = emb[base + c] + pos[(long)(s + 1) * 768 + c] + tok[c];
    x[i] = v; s1 += v; s2 += v * v;
  }
  float mean, inv;
  block_stats(s1, s2, red, mean, inv);
#pragma unroll
  for (int i = 0; i < 3; ++i) {
    int c = t + i * 256;
    float y = (x[i] - mean) * inv * g[c] + bta[c];
    h32[base + c] = y;
    hbf[base + c] = (bf16)y;
  }
}

// h = LN(h32 + p0 + p1 + bias) ; write back h32 and bf16 copy.
__global__ __launch_bounds__(256) void add_ln_kernel(
    float* __restrict__ h32, const float* __restrict__ p0,
    const float* __restrict__ p1, const float* __restrict__ bias,
    const float* __restrict__ g, const float* __restrict__ bta,
    bf16* __restrict__ hbf) {
  __shared__ float red[8];
  const long base = (long)blockIdx.x * 768;
  const int t = threadIdx.x;
  float x[3], s1 = 0.f, s2 = 0.f;
#pragma unroll
  for (int i = 0; i < 3; ++i) {
    int c = t + i * 256;
    float v = h32[base + c] + p0[base + c] + p1[base + c] + bias[c];
    x[i] = v; s1 += v; s2 += v * v;
  }
  float mean, inv;
  block_stats(s1, s2, red, mean, inv);
#pragma unroll
  for (int i = 0; i < 3; ++i) {
    int c = t + i * 256;
    float y = (x[i] - mean) * inv * g[c] + bta[c];
    h32[base + c] = y;
    hbf[base + c] = (bf16)y;
  }
}

// ------------------------------- GEMM --------------------------------------
// C[M,N] = A[M,K] @ W[K,N] (+ bias), BT = W^T bf16 [N][ld].
// 128x128 tile, BK=64, 4 waves each 64x64, global_load_lds staging.
// MODE: 0 = fp32 partial store (split-K via blockIdx.z, NO bias)
//       1 = bf16 store + bias
//       2 = bf16 store + bias + tanh-GELU
template <int MODE>
__global__ __launch_bounds__(256) void gemm_kernel(
    const bf16* __restrict__ A, const bf16* __restrict__ BT,
    const float* __restrict__ bias, void* __restrict__ C0, void* __restrict__ C1,
    int N, int ld, int ksize) {
  __shared__ bf16 As[128 * 64];
  __shared__ bf16 Bs[128 * 64];
  const int tid  = threadIdx.x;
  const int wave = tid >> 6, lane = tid & 63, l15 = lane & 15, quad = lane >> 4;
  const int wm = wave >> 1, wn = wave & 1;
  const long m0 = (long)blockIdx.y * 128;
  const int  n0 = blockIdx.x * 128;
  const int  k0 = blockIdx.z * ksize;

  floatx4 acc[4][4] = {};
  const bf16* Ag = A + m0 * ld + k0;
  const bf16* Bg = BT + (long)n0 * ld + k0;
  const int rowoff = tid >> 3, sc = tid & 7;

  for (int kt = 0; kt < ksize; kt += 64) {
#pragma unroll
    for (int p = 0; p < 4; ++p) {
      const int row = p * 32 + rowoff;
      gld_lds16(Ag + (long)row * ld + kt + sc * 8, &As[p * 2048 + wave * 512]);
      gld_lds16(Bg + (long)row * ld + kt + sc * 8, &Bs[p * 2048 + wave * 512]);
    }
    __syncthreads();
#pragma unroll
    for (int kk = 0; kk < 2; ++kk) {
      const int ko = kk * 32 + quad * 8;
      bf16x8 af[4], bfr[4];
#pragma unroll
      for (int mt = 0; mt < 4; ++mt)
        af[mt] = *(const bf16x8*)&As[(wm * 64 + mt * 16 + l15) * 64 + ko];
#pragma unroll
      for (int nt = 0; nt < 4; ++nt)
        bfr[nt] = *(const bf16x8*)&Bs[(wn * 64 + nt * 16 + l15) * 64 + ko];
#pragma unroll
      for (int mt = 0; mt < 4; ++mt)
#pragma unroll
        for (int nt = 0; nt < 4; ++nt)
          acc[mt][nt] = MFMA16(af[mt], bfr[nt], acc[mt][nt]);
    }
    __syncthreads();
  }

  float* Cp32 = (MODE == 0) ? ((blockIdx.z == 0) ? (float*)C0 : (float*)C1) : nullptr;
#pragma unroll
  for (int nt = 0; nt < 4; ++nt) {
    const int col = n0 + wn * 64 + nt * 16 + l15;
    const float bb = (MODE == 0) ? 0.f : bias[col];
#pragma unroll
    for (int mt = 0; mt < 4; ++mt) {
      const long row = m0 + wm * 64 + mt * 16 + quad * 4;
#pragma unroll
      for (int r = 0; r < 4; ++r) {
        float v = acc[mt][nt][r] + bb;
        if (MODE == 2) v = gelu_tanh(v);
        if (MODE == 0) Cp32[(row + r) * N + col] = v;
        else           ((bf16*)C0)[(row + r) * N + col] = (bf16)v;
      }
    }
  }
}

// ----------------------------- attention -----------------------------------
__global__ __launch_bounds__(256) void attn_kernel(
    const bf16* __restrict__ qkv, const int* __restrict__ amask,
    bf16* __restrict__ attn_out) {
  constexpr int S = 4096, HID3 = 2304;
  __shared__ bf16 Ss[64 * 328];
  __shared__ bf16 Ts[64 * 72];

  const int q0 = blockIdx.x * 64, h = blockIdx.y, b = blockIdx.z;
  const int tid = threadIdx.x, wave = tid >> 6, lane = tid & 63;
  const int l15 = lane & 15, quad = lane >> 4;

  const bf16* Qb = qkv + (long)b * S * HID3 + h * 64;
  const bf16* Kb = Qb + 768;
  const bf16* Vb = Qb + 1536;

  bf16x8 qf[2];
  {
    const long qrow = q0 + wave * 16 + l15;
    qf[0] = *(const bf16x8*)&Qb[qrow * HID3 + quad * 8];
    qf[1] = *(const bf16x8*)&Qb[qrow * HID3 + 32 + quad * 8];
  }

  float mrow[4] = {-3e38f, -3e38f, -3e38f, -3e38f};

  // ---- Phase A: scores ----
  for (int t = 0; t < 5; ++t) {
    const int j0 = q0 - 128 + t * 64;
    __syncthreads();
    for (int i = tid; i < 512; i += 256) {
      const int key = i >> 3, sc2 = i & 7, j = j0 + key;
      uint4 val = make_uint4(0u, 0u, 0u, 0u);
      if (j >= 0 && j < S) val = *(const uint4*)&Kb[(long)j * HID3 + sc2 * 8];
      *(uint4*)&Ts[key * 72 + sc2 * 8] = val;
    }
    __syncthreads();
    floatx4 sacc[4] = {};
#pragma unroll
    for (int kk = 0; kk < 2; ++kk) {
      const int ko = kk * 32 + quad * 8;
#pragma unroll
      for (int nt = 0; nt < 4; ++nt) {
        bf16x8 kf = *(const bf16x8*)&Ts[(nt * 16 + l15) * 72 + ko];
        sacc[nt] = MFMA16(qf[kk], kf, sacc[nt]);
      }
    }
#pragma unroll
    for (int nt = 0; nt < 4; ++nt) {
      const int jj = t * 64 + nt * 16 + l15;
      const int j = j0 + nt * 16 + l15;
      bool jv = (j >= 0) && (j < S);
      if (jv) jv = (amask[b * S + j] != 0);
#pragma unroll
      for (int r = 0; r < 4; ++r) {
        const int qi = wave * 16 + quad * 4 + r;
        const bool ok = jv && (jj >= qi) && (jj <= qi + 256);
        const float sv = ok ? sacc[nt][r] * 0.125f : -1e9f;
        mrow[r] = fmaxf(mrow[r], sv);
        Ss[(wave * 16 + quad * 4 + r) * 328 + jj] = (bf16)sv;
      }
    }
  }
#pragma unroll
  for (int off = 1; off < 16; off <<= 1)
#pragma unroll
    for (int r = 0; r < 4; ++r)
      mrow[r] = fmaxf(mrow[r], __shfl_xor(mrow[r], off, 64));

  __syncthreads();

  // ---- Phase B: softmax ----
  float ssum[4] = {0.f, 0.f, 0.f, 0.f};
  for (int i = 0; i < 20; ++i) {
#pragma unroll
    for (int r = 0; r < 4; ++r) {
      const int idx = (wave * 16 + quad * 4 + r) * 328 + i * 16 + l15;
      const float sv = (float)Ss[idx];
      const float p = __expf(sv - mrow[r]);
      ssum[r] += p;
      Ss[idx] = (bf16)p;
    }
  }
#pragma unroll
  for (int off = 1; off < 16; off <<= 1)
#pragma unroll
    for (int r = 0; r < 4; ++r) ssum[r] += __shfl_xor(ssum[r], off, 64);
  float inv[4];
#pragma unroll
  for (int r = 0; r < 4; ++r) inv[r] = 1.f / ssum[r];

  // ---- Phase C: P @ V ----
  floatx4 oacc[4] = {};
  for (int t = 0; t < 5; ++t) {
    const int j0 = q0 - 128 + t * 64;
    __syncthreads();
    for (int i = tid; i < 512; i += 256) {
      const int key = i >> 3, ds = i & 7, j = j0 + key;
      if (j >= 0 && j < S) {
        bf16x8 v = *(const bf16x8*)&Vb[(long)j * HID3 + ds * 8];
#pragma unroll
        for (int u = 0; u < 8; ++u) Ts[(ds * 8 + u) * 72 + key] = v[u];
      } else {
#pragma unroll
        for (int u = 0; u < 8; ++u) Ts[(ds * 8 + u) * 72 + key] = (bf16)0.f;
      }
    }
    __syncthreads();
#pragma unroll
    for (int kk = 0; kk < 2; ++kk) {
      const int ko = kk * 32 + quad * 8;
      bf16x8 pf = *(const bf16x8*)&Ss[(wave * 16 + l15) * 328 + t * 64 + ko];
#pragma unroll
      for (int nt = 0; nt < 4; ++nt) {
        bf16x8 vf = *(const bf16x8*)&Ts[(nt * 16 + l15) * 72 + ko];
        oacc[nt] = MFMA16(pf, vf, oacc[nt]);
      }
    }
  }

  const long orow = (long)b * S + q0 + wave * 16 + quad * 4;
#pragma unroll
  for (int nt = 0; nt < 4; ++nt)
#pragma unroll
    for (int r = 0; r < 4; ++r)
      attn_out[(orow + r) * 768 + h * 64 + nt * 16 + l15] =
          (bf16)(oacc[nt][r] * inv[r]);
}

// ------------------------------ final head ---------------------------------
__global__ __launch_bounds__(256) void final_kernel(
    const float* __restrict__ h32, const float* __restrict__ Wp,
    const float* __restrict__ bp, float* __restrict__ out) {
  const int wave = threadIdx.x >> 6, lane = threadIdx.x & 63;
  const long tok = (long)blockIdx.x * 4 + wave;
  float s = 0.f;
#pragma unroll
  for (int i = 0; i < 12; ++i) {
    const int c = lane + i * 64;
    s += h32[tok * 768 + c] * Wp[c];
  }
#pragma unroll
  for (int off = 32; off > 0; off >>= 1) s += __shfl_down(s, off, 64);
  if (lane == 0) out[tok] = 1.f / (1.f + __expf(-(s + bp[0])));
}

// ------------------------------ launcher -----------------------------------
extern "C" void kernel_launch(void* const* d_in, const int* in_sizes, int n_in,
                              void* d_out, int out_size, void* d_ws, size_t ws_size,
                              hipStream_t stream) {
  const float* emb   = (const float*)d_in[0];
  const int*   amask = (const int*)d_in[1];
  const float* pos   = (const float*)d_in[2];
  const float* tok   = (const float*)d_in[3];
  const float* elng  = (const float*)d_in[4];
  const float* elnb  = (const float*)d_in[5];
  const float* Wq = (const float*)d_in[6];   const float* bq = (const float*)d_in[7];
  const float* Wk = (const float*)d_in[8];   const float* bk = (const float*)d_in[9];
  const float* Wv = (const float*)d_in[10];  const float* bv = (const float*)d_in[11];
  const float* Wo = (const float*)d_in[12];  const float* bo = (const float*)d_in[13];
  const float* ln1g = (const float*)d_in[14]; const float* ln1b = (const float*)d_in[15];
  const float* Wi = (const float*)d_in[16];  const float* bi = (const float*)d_in[17];
  const float* Wf = (const float*)d_in[18];  const float* bfb = (const float*)d_in[19];
  const float* ln2g = (const float*)d_in[20]; const float* ln2b = (const float*)d_in[21];
  const float* Wp = (const float*)d_in[22];  const float* bp = (const float*)d_in[23];
  float* out = (float*)d_out;

  char* ws = (char*)d_ws;
  bf16*  WTqkv = (bf16*)(ws + OFF_WTQKV);
  bf16*  WTo   = (bf16*)(ws + OFF_WTO);
  bf16*  WTi   = (bf16*)(ws + OFF_WTI);
  bf16*  WTf   = (bf16*)(ws + OFF_WTF);
  float* bqkv  = (float*)(ws + OFF_BQKV);
  float* h32   = (float*)(ws + OFF_H32);
  bf16*  hbf   = (bf16*)(ws + OFF_HBF);
  bf16*  qkvb  = (bf16*)(ws + OFF_QKV);
  float* part1 = (float*)(ws + OFF_QKV);   // fp32 overlay; qkvb dead after attn
  bf16*  attnb = (bf16*)(ws + OFF_ATTN);
  float* tmp   = (float*)(ws + OFF_TMP);
  bf16*  ffn1  = (bf16*)(ws + OFF_FFN1);

  const dim3 tb(32, 8, 1);
  transpose_cast<<<dim3(24, 24, 4), tb, 0, stream>>>(Wq, WTqkv,               768, 768,  (long)768 * 768,  (long)2304 * 768);
  transpose_cast<<<dim3(24, 24, 4), tb, 0, stream>>>(Wk, WTqkv + 768 * 768,   768, 768,  (long)768 * 768,  (long)2304 * 768);
  transpose_cast<<<dim3(24, 24, 4), tb, 0, stream>>>(Wv, WTqkv + 1536 * 768,  768, 768,  (long)768 * 768,  (long)2304 * 768);
  transpose_cast<<<dim3(24, 24, 4), tb, 0, stream>>>(Wo, WTo,                 768, 768,  (long)768 * 768,  (long)768 * 768);
  transpose_cast<<<dim3(96, 24, 4), tb, 0, stream>>>(Wi, WTi,                 768, 3072, (long)768 * 3072, (long)3072 * 768);
  transpose_cast<<<dim3(24, 96, 4), tb, 0, stream>>>(Wf, WTf,                 3072, 768, (long)3072 * 768, (long)768 * 3072);
  bias_concat<<<36, 256, 0, stream>>>(bq, bk, bv, bqkv);

  embed_ln_kernel<<<8192, 256, 0, stream>>>(emb, pos, tok, elng, elnb, h32, hbf);

  for (int l = 0; l < 4; ++l) {
    gemm_kernel<1><<<dim3(18, 64, 1), 256, 0, stream>>>(
        hbf, WTqkv + (size_t)l * 2304 * 768, bqkv + l * 2304, qkvb, nullptr, 2304, 768, 768);
    attn_kernel<<<dim3(64, 12, 2), 256, 0, stream>>>(qkvb, amask, attnb);
    // O-proj: split-K=2 (K=768 -> 2x384), partials tmp / part1 (qkv overlay)
    gemm_kernel<0><<<dim3(6, 64, 2), 256, 0, stream>>>(
        attnb, WTo + (size_t)l * 768 * 768, nullptr, tmp, part1, 768, 768, 384);
    add_ln_kernel<<<8192, 256, 0, stream>>>(h32, tmp, part1, bo + l * 768,
                                            ln1g + l * 768, ln1b + l * 768, hbf);
    gemm_kernel<2><<<dim3(24, 64, 1), 256, 0, stream>>>(
        hbf, WTi + (size_t)l * 3072 * 768, bi + l * 3072, ffn1, nullptr, 3072, 768, 768);
    // FFN2: split-K=2 (K=3072 -> 2x1536)
    gemm_kernel<0><<<dim3(6, 64, 2), 256, 0, stream>>>(
        ffn1, WTf + (size_t)l * 768 * 3072, nullptr, tmp, part1, 768, 3072, 1536);
    add_ln_kernel<<<8192, 256, 0, stream>>>(h32, tmp, part1, bfb + l * 768,
                                            ln2g + l * 768, ln2b + l * 768, hbf);
  }

  final_kernel<<<2048, 256, 0, stream>>>(h32, Wp, bp, out);
}

// Round 3
// 1532.641 us; speedup vs baseline: 1.0073x; 1.0065x over previous
//
#include <hip/hip_runtime.h>
#include <hip/hip_bf16.h>

// ---------------------------------------------------------------------------
// Longformer-style forward: B=2, S=4096, HID=768, L=4, H=12, D=64, W=128
// R3: m-major grid (XCD L2 locality: id%8 = m%8 keeps A-slab on one XCD),
//     attention rebuilt: pre-transposed V, global_load_lds staging, edge-tile
//     skip, vectorized softmax pass.
// ---------------------------------------------------------------------------

typedef __bf16 bf16;
typedef bf16  bf16x8  __attribute__((ext_vector_type(8)));
typedef float floatx4 __attribute__((ext_vector_type(4)));

#define MFMA16(a, b, c) __builtin_amdgcn_mfma_f32_16x16x32_bf16((a), (b), (c), 0, 0, 0)

__device__ __forceinline__ void gld_lds16(const bf16* gp, bf16* lp) {
  __builtin_amdgcn_global_load_lds(
      (const __attribute__((address_space(1))) void*)gp,
      (__attribute__((address_space(3))) void*)lp, 16, 0, 0);
}

__device__ __forceinline__ float gelu_tanh(float v) {
  float t = 0.7978845608028654f * (v + 0.044715f * v * v * v);
  float e = __expf(2.f * t);
  float th = 1.f - 2.f / (e + 1.f);
  return 0.5f * v * (1.f + th);
}

// ------------------------- workspace layout (bytes) ------------------------
static constexpr size_t SZ_WTQKV = (size_t)4 * 2304 * 768 * 2;
static constexpr size_t SZ_WTO   = (size_t)4 * 768 * 768 * 2;
static constexpr size_t SZ_WTI   = (size_t)4 * 3072 * 768 * 2;
static constexpr size_t SZ_WTF   = (size_t)4 * 768 * 3072 * 2;
static constexpr size_t SZ_BQKV  = (size_t)4 * 2304 * 4;
static constexpr size_t SZ_H32   = (size_t)8192 * 768 * 4;
static constexpr size_t SZ_HBF   = (size_t)8192 * 768 * 2;
static constexpr size_t SZ_QKV   = (size_t)8192 * 2304 * 2;
static constexpr size_t SZ_ATTN  = (size_t)8192 * 768 * 2;
static constexpr size_t SZ_TMP   = (size_t)8192 * 768 * 4;   // also holds Vt (12.6MB)

static constexpr size_t OFF_WTQKV = 0;
static constexpr size_t OFF_WTO   = OFF_WTQKV + SZ_WTQKV;
static constexpr size_t OFF_WTI   = OFF_WTO   + SZ_WTO;
static constexpr size_t OFF_WTF   = OFF_WTI   + SZ_WTI;
static constexpr size_t OFF_BQKV  = OFF_WTF   + SZ_WTF;
static constexpr size_t OFF_H32   = OFF_BQKV  + SZ_BQKV;
static constexpr size_t OFF_HBF   = OFF_H32   + SZ_H32;
static constexpr size_t OFF_QKV   = OFF_HBF   + SZ_HBF;
static constexpr size_t OFF_ATTN  = OFF_QKV   + SZ_QKV;
static constexpr size_t OFF_TMP   = OFF_ATTN  + SZ_ATTN;
static constexpr size_t OFF_FFN1  = OFF_TMP   + SZ_TMP;

// ------------------------- weight transpose + cast -------------------------
__global__ __launch_bounds__(256) void transpose_cast(
    const float* __restrict__ src, bf16* __restrict__ dst,
    int K, int N, long sStride, long dStride) {
  __shared__ float tile[32][33];
  const int l = blockIdx.z;
  src += (long)l * sStride;
  dst += (long)l * dStride;
  const int n0 = blockIdx.x * 32, k0 = blockIdx.y * 32;
  const int tx = threadIdx.x, ty = threadIdx.y; // (32,8)
#pragma unroll
  for (int i = 0; i < 4; ++i)
    tile[ty + i * 8][tx] = src[(long)(k0 + ty + i * 8) * N + n0 + tx];
  __syncthreads();
#pragma unroll
  for (int i = 0; i < 4; ++i)
    dst[(long)(n0 + ty + i * 8) * K + k0 + tx] = (bf16)tile[tx][ty + i * 8];
}

__global__ void bias_concat(const float* __restrict__ bq, const float* __restrict__ bk,
                            const float* __restrict__ bv, float* __restrict__ bqkv) {
  int i = blockIdx.x * 256 + threadIdx.x; // 4*2304
  if (i >= 4 * 2304) return;
  int l = i / 2304, p = i % 2304;
  float v = (p < 768) ? bq[l * 768 + p]
          : (p < 1536) ? bk[l * 768 + p - 768] : bv[l * 768 + p - 1536];
  bqkv[i] = v;
}

// ------------------------------ LN helpers ---------------------------------
__device__ __forceinline__ void block_stats(float s1, float s2, float* red,
                                            float& mean, float& inv) {
  const int lane = threadIdx.x & 63, wave = threadIdx.x >> 6;
#pragma unroll
  for (int off = 32; off > 0; off >>= 1) {
    s1 += __shfl_down(s1, off, 64);
    s2 += __shfl_down(s2, off, 64);
  }
  if (lane == 0) { red[wave] = s1; red[4 + wave] = s2; }
  __syncthreads();
  s1 = red[0] + red[1] + red[2] + red[3];
  s2 = red[4] + red[5] + red[6] + red[7];
  mean = s1 * (1.f / 768.f);
  float var = s2 * (1.f / 768.f) - mean * mean;
  inv = rsqrtf(var + 1e-12f);
}

__global__ __launch_bounds__(256) void embed_ln_kernel(
    const float* __restrict__ emb, const float* __restrict__ pos,
    const float* __restrict__ tok, const float* __restrict__ g,
    const float* __restrict__ bta, float* __restrict__ h32, bf16* __restrict__ hbf) {
  __shared__ float red[8];
  const long base = (long)blockIdx.x * 768;
  const int s = blockIdx.x & 4095;
  const int t = threadIdx.x;
  float x[3], s1 = 0.f, s2 = 0.f;
#pragma unroll
  for (int i = 0; i < 3; ++i) {
    int c = t + i * 256;
    float v = emb[base + c] + pos[(long)(s + 1) * 768 + c] + tok[c];
    x[i] = v; s1 += v; s2 += v * v;
  }
  float mean, inv;
  block_stats(s1, s2, red, mean, inv);
#pragma unroll
  for (int i = 0; i < 3; ++i) {
    int c = t + i * 256;
    float y = (x[i] - mean) * inv * g[c] + bta[c];
    h32[base + c] = y;
    hbf[base + c] = (bf16)y;
  }
}

__global__ __launch_bounds__(256) void add_ln_kernel(
    float* __restrict__ h32, const float* __restrict__ p0,
    const float* __restrict__ p1, const float* __restrict__ bias,
    const float* __restrict__ g, const float* __restrict__ bta,
    bf16* __restrict__ hbf) {
  __shared__ float red[8];
  const long base = (long)blockIdx.x * 768;
  const int t = threadIdx.x;
  float x[3], s1 = 0.f, s2 = 0.f;
#pragma unroll
  for (int i = 0; i < 3; ++i) {
    int c = t + i * 256;
    float v = h32[base + c] + p0[base + c] + p1[base + c] + bias[c];
    x[i] = v; s1 += v; s2 += v * v;
  }
  float mean, inv;
  block_stats(s1, s2, red, mean, inv);
#pragma unroll
  for (int i = 0; i < 3; ++i) {
    int c = t + i * 256;
    float y = (x[i] - mean) * inv * g[c] + bta[c];
    h32[base + c] = y;
    hbf[base + c] = (bf16)y;
  }
}

// ------------------------------- GEMM --------------------------------------
// m-major grid: blockIdx.x = M-block (gridX=64, multiple of 8 so id%8=x%8 ->
// all n/z blocks of one A-slab share an XCD L2). MODE: 0=fp32 partial (split-K
// via z, no bias), 1=bf16+bias, 2=bf16+bias+tanh-GELU.
template <int MODE>
__global__ __launch_bounds__(256) void gemm_kernel(
    const bf16* __restrict__ A, const bf16* __restrict__ BT,
    const float* __restrict__ bias, void* __restrict__ C0, void* __restrict__ C1,
    int N, int ld, int ksize) {
  __shared__ bf16 As[128 * 64];
  __shared__ bf16 Bs[128 * 64];
  const int tid  = threadIdx.x;
  const int wave = tid >> 6, lane = tid & 63, l15 = lane & 15, quad = lane >> 4;
  const int wm = wave >> 1, wn = wave & 1;
  const long m0 = (long)blockIdx.x * 128;
  const int  n0 = blockIdx.y * 128;
  const int  k0 = blockIdx.z * ksize;

  floatx4 acc[4][4] = {};
  const bf16* Ag = A + m0 * ld + k0;
  const bf16* Bg = BT + (long)n0 * ld + k0;
  const int rowoff = tid >> 3, sc = tid & 7;

  for (int kt = 0; kt < ksize; kt += 64) {
#pragma unroll
    for (int p = 0; p < 4; ++p) {
      const int row = p * 32 + rowoff;
      gld_lds16(Ag + (long)row * ld + kt + sc * 8, &As[p * 2048 + wave * 512]);
      gld_lds16(Bg + (long)row * ld + kt + sc * 8, &Bs[p * 2048 + wave * 512]);
    }
    __syncthreads();
#pragma unroll
    for (int kk = 0; kk < 2; ++kk) {
      const int ko = kk * 32 + quad * 8;
      bf16x8 af[4], bfr[4];
#pragma unroll
      for (int mt = 0; mt < 4; ++mt)
        af[mt] = *(const bf16x8*)&As[(wm * 64 + mt * 16 + l15) * 64 + ko];
#pragma unroll
      for (int nt = 0; nt < 4; ++nt)
        bfr[nt] = *(const bf16x8*)&Bs[(wn * 64 + nt * 16 + l15) * 64 + ko];
#pragma unroll
      for (int mt = 0; mt < 4; ++mt)
#pragma unroll
        for (int nt = 0; nt < 4; ++nt)
          acc[mt][nt] = MFMA16(af[mt], bfr[nt], acc[mt][nt]);
    }
    __syncthreads();
  }

  float* Cp32 = (MODE == 0) ? ((blockIdx.z == 0) ? (float*)C0 : (float*)C1) : nullptr;
#pragma unroll
  for (int nt = 0; nt < 4; ++nt) {
    const int col = n0 + wn * 64 + nt * 16 + l15;
    const float bb = (MODE == 0) ? 0.f : bias[col];
#pragma unroll
    for (int mt = 0; mt < 4; ++mt) {
      const long row = m0 + wm * 64 + mt * 16 + quad * 4;
#pragma unroll
      for (int r = 0; r < 4; ++r) {
        float v = acc[mt][nt][r] + bb;
        if (MODE == 2) v = gelu_tanh(v);
        if (MODE == 0) Cp32[(row + r) * N + col] = v;
        else           ((bf16*)C0)[(row + r) * N + col] = (bf16)v;
      }
    }
  }
}

// -------------------- V transpose: qkv V-part -> Vt[b,h][d][S] -------------
__global__ __launch_bounds__(256) void vtrans_kernel(
    const bf16* __restrict__ qkv, bf16* __restrict__ vt) {
  __shared__ bf16 tile[64 * 68];
  const int s0 = blockIdx.x * 64, h = blockIdx.y, b = blockIdx.z;
  const int tid = threadIdx.x;
  const bf16* src = qkv + (long)b * 4096 * 2304 + 1536 + h * 64;
#pragma unroll
  for (int p = 0; p < 2; ++p) {
    const int i = p * 256 + tid;
    const int r = i >> 3, c = i & 7;
    *(uint4*)&tile[r * 68 + c * 8] = *(const uint4*)&src[(long)(s0 + r) * 2304 + c * 8];
  }
  __syncthreads();
  bf16* dst = vt + ((long)(b * 12 + h)) * 64 * 4096;
#pragma unroll
  for (int p = 0; p < 2; ++p) {
    const int i = p * 256 + tid;
    const int d = i >> 3, cs = i & 7;
    bf16 vals[8];
#pragma unroll
    for (int u = 0; u < 8; ++u) vals[u] = tile[(cs * 8 + u) * 68 + d];
    *(uint4*)&dst[(long)d * 4096 + s0 + cs * 8] = *(const uint4*)vals;
  }
}

// ----------------------------- attention -----------------------------------
// One block = (b, h, 64-query chunk x). Tiles t: j0=(x-2+t)*64, each fully
// in-range or fully OOB -> loop only valid t in [t_lo, t_hi).
__global__ __launch_bounds__(256) void attn_kernel(
    const bf16* __restrict__ qkv, const bf16* __restrict__ vt,
    const int* __restrict__ amask, bf16* __restrict__ attn_out) {
  constexpr int S = 4096, HID3 = 2304;
  __shared__ bf16 Ss[64 * 328];
  __shared__ bf16 Ts[64 * 64];
  __shared__ float redm[64], reds[64];

  const int x = blockIdx.x, q0 = x * 64, h = blockIdx.y, b = blockIdx.z;
  const int tid = threadIdx.x, wave = tid >> 6, lane = tid & 63;
  const int l15 = lane & 15, quad = lane >> 4;
  const int rowoff = tid >> 3, sc = tid & 7;
  const int t_lo = (x < 2) ? (2 - x) : 0;
  const int t_hi = (x > 61) ? (66 - x) : 5;

  const bf16* Qb = qkv + (long)b * S * HID3 + h * 64;
  const bf16* Kb = Qb + 768;
  const bf16* Vt_bh = vt + ((long)(b * 12 + h)) * 64 * 4096;

  bf16x8 qf[2];
  {
    const long qrow = q0 + wave * 16 + l15;
    qf[0] = *(const bf16x8*)&Qb[qrow * HID3 + quad * 8];
    qf[1] = *(const bf16x8*)&Qb[qrow * HID3 + 32 + quad * 8];
  }

  float mrow[4] = {-3e38f, -3e38f, -3e38f, -3e38f};

  // ---- Phase A: scores ----
  for (int t = t_lo; t < t_hi; ++t) {
    const int j0 = (x - 2 + t) * 64;
    __syncthreads();
#pragma unroll
    for (int p = 0; p < 2; ++p) {
      const int key = p * 32 + rowoff;
      gld_lds16(Kb + (long)(j0 + key) * HID3 + sc * 8, &Ts[p * 2048 + wave * 512]);
    }
    __syncthreads();
    floatx4 sacc[4] = {};
#pragma unroll
    for (int kk = 0; kk < 2; ++kk) {
      const int ko = kk * 32 + quad * 8;
#pragma unroll
      for (int nt = 0; nt < 4; ++nt) {
        bf16x8 kf = *(const bf16x8*)&Ts[(nt * 16 + l15) * 64 + ko];
        sacc[nt] = MFMA16(qf[kk], kf, sacc[nt]);
      }
    }
#pragma unroll
    for (int nt = 0; nt < 4; ++nt) {
      const int jj = t * 64 + nt * 16 + l15;
      const int j = j0 + nt * 16 + l15;
      const bool jv = (amask[b * S + j] != 0);
#pragma unroll
      for (int r = 0; r < 4; ++r) {
        const int qi = wave * 16 + quad * 4 + r;
        const bool ok = jv && (jj >= qi) && (jj <= qi + 256);
        const float sv = ok ? sacc[nt][r] * 0.125f : -1e9f;
        mrow[r] = fmaxf(mrow[r], sv);
        Ss[(wave * 16 + quad * 4 + r) * 328 + jj] = (bf16)sv;
      }
    }
  }
#pragma unroll
  for (int off = 1; off < 16; off <<= 1)
#pragma unroll
    for (int r = 0; r < 4; ++r)
      mrow[r] = fmaxf(mrow[r], __shfl_xor(mrow[r], off, 64));
  if (l15 == 0) {
#pragma unroll
    for (int r = 0; r < 4; ++r) redm[wave * 16 + quad * 4 + r] = mrow[r];
  }
  __syncthreads();

  // ---- Phase B: softmax pass (rows re-owned by l15, chunks by quad) ----
  {
    const int row = wave * 16 + l15;
    const float mx = redm[row];
    float sum = 0.f;
    for (int c = t_lo * 8 + quad; c < t_hi * 8; c += 4) {
      bf16x8 pv = *(const bf16x8*)&Ss[row * 328 + c * 8];
#pragma unroll
      for (int u = 0; u < 8; ++u) {
        const float p = __expf((float)pv[u] - mx);
        sum += p;
        pv[u] = (bf16)p;
      }
      *(bf16x8*)&Ss[row * 328 + c * 8] = pv;
    }
    sum += __shfl_xor(sum, 16, 64);
    sum += __shfl_xor(sum, 32, 64);
    if (quad == 0) reds[row] = sum;
  }
  __syncthreads();

  // ---- Phase C: P @ V with pre-transposed V ----
  floatx4 oacc[4] = {};
  for (int t = t_lo; t < t_hi; ++t) {
    const int j0 = (x - 2 + t) * 64;
    __syncthreads();
#pragma unroll
    for (int p = 0; p < 2; ++p) {
      const int d = p * 32 + rowoff;
      gld_lds16(Vt_bh + (long)d * 4096 + j0 + sc * 8, &Ts[p * 2048 + wave * 512]);
    }
    __syncthreads();
#pragma unroll
    for (int kk = 0; kk < 2; ++kk) {
      const int ko = kk * 32 + quad * 8;
      bf16x8 pf = *(const bf16x8*)&Ss[(wave * 16 + l15) * 328 + t * 64 + ko];
#pragma unroll
      for (int nt = 0; nt < 4; ++nt) {
        bf16x8 vf = *(const bf16x8*)&Ts[(nt * 16 + l15) * 64 + ko];
        oacc[nt] = MFMA16(pf, vf, oacc[nt]);
      }
    }
  }

  float inv[4];
#pragma unroll
  for (int r = 0; r < 4; ++r) inv[r] = 1.f / reds[wave * 16 + quad * 4 + r];
  const long orow = (long)b * S + q0 + wave * 16 + quad * 4;
#pragma unroll
  for (int nt = 0; nt < 4; ++nt)
#pragma unroll
    for (int r = 0; r < 4; ++r)
      attn_out[(orow + r) * 768 + h * 64 + nt * 16 + l15] =
          (bf16)(oacc[nt][r] * inv[r]);
}

// ------------------------------ final head ---------------------------------
__global__ __launch_bounds__(256) void final_kernel(
    const float* __restrict__ h32, const float* __restrict__ Wp,
    const float* __restrict__ bp, float* __restrict__ out) {
  const int wave = threadIdx.x >> 6, lane = threadIdx.x & 63;
  const long tok = (long)blockIdx.x * 4 + wave;
  float s = 0.f;
#pragma unroll
  for (int i = 0; i < 12; ++i) {
    const int c = lane + i * 64;
    s += h32[tok * 768 + c] * Wp[c];
  }
#pragma unroll
  for (int off = 32; off > 0; off >>= 1) s += __shfl_down(s, off, 64);
  if (lane == 0) out[tok] = 1.f / (1.f + __expf(-(s + bp[0])));
}

// ------------------------------ launcher -----------------------------------
extern "C" void kernel_launch(void* const* d_in, const int* in_sizes, int n_in,
                              void* d_out, int out_size, void* d_ws, size_t ws_size,
                              hipStream_t stream) {
  const float* emb   = (const float*)d_in[0];
  const int*   amask = (const int*)d_in[1];
  const float* pos   = (const float*)d_in[2];
  const float* tok   = (const float*)d_in[3];
  const float* elng  = (const float*)d_in[4];
  const float* elnb  = (const float*)d_in[5];
  const float* Wq = (const float*)d_in[6];   const float* bq = (const float*)d_in[7];
  const float* Wk = (const float*)d_in[8];   const float* bk = (const float*)d_in[9];
  const float* Wv = (const float*)d_in[10];  const float* bv = (const float*)d_in[11];
  const float* Wo = (const float*)d_in[12];  const float* bo = (const float*)d_in[13];
  const float* ln1g = (const float*)d_in[14]; const float* ln1b = (const float*)d_in[15];
  const float* Wi = (const float*)d_in[16];  const float* bi = (const float*)d_in[17];
  const float* Wf = (const float*)d_in[18];  const float* bfb = (const float*)d_in[19];
  const float* ln2g = (const float*)d_in[20]; const float* ln2b = (const float*)d_in[21];
  const float* Wp = (const float*)d_in[22];  const float* bp = (const float*)d_in[23];
  float* out = (float*)d_out;

  char* ws = (char*)d_ws;
  bf16*  WTqkv = (bf16*)(ws + OFF_WTQKV);
  bf16*  WTo   = (bf16*)(ws + OFF_WTO);
  bf16*  WTi   = (bf16*)(ws + OFF_WTI);
  bf16*  WTf   = (bf16*)(ws + OFF_WTF);
  float* bqkv  = (float*)(ws + OFF_BQKV);
  float* h32   = (float*)(ws + OFF_H32);
  bf16*  hbf   = (bf16*)(ws + OFF_HBF);
  bf16*  qkvb  = (bf16*)(ws + OFF_QKV);
  float* part1 = (float*)(ws + OFF_QKV);   // fp32 overlay; qkvb dead after attn
  bf16*  attnb = (bf16*)(ws + OFF_ATTN);
  float* tmp   = (float*)(ws + OFF_TMP);
  bf16*  vtb   = (bf16*)(ws + OFF_TMP);    // Vt overlay; tmp dead during attn
  bf16*  ffn1  = (bf16*)(ws + OFF_FFN1);

  const dim3 tb(32, 8, 1);
  transpose_cast<<<dim3(24, 24, 4), tb, 0, stream>>>(Wq, WTqkv,               768, 768,  (long)768 * 768,  (long)2304 * 768);
  transpose_cast<<<dim3(24, 24, 4), tb, 0, stream>>>(Wk, WTqkv + 768 * 768,   768, 768,  (long)768 * 768,  (long)2304 * 768);
  transpose_cast<<<dim3(24, 24, 4), tb, 0, stream>>>(Wv, WTqkv + 1536 * 768,  768, 768,  (long)768 * 768,  (long)2304 * 768);
  transpose_cast<<<dim3(24, 24, 4), tb, 0, stream>>>(Wo, WTo,                 768, 768,  (long)768 * 768,  (long)768 * 768);
  transpose_cast<<<dim3(96, 24, 4), tb, 0, stream>>>(Wi, WTi,                 768, 3072, (long)768 * 3072, (long)3072 * 768);
  transpose_cast<<<dim3(24, 96, 4), tb, 0, stream>>>(Wf, WTf,                 3072, 768, (long)3072 * 768, (long)768 * 3072);
  bias_concat<<<36, 256, 0, stream>>>(bq, bk, bv, bqkv);

  embed_ln_kernel<<<8192, 256, 0, stream>>>(emb, pos, tok, elng, elnb, h32, hbf);

  for (int l = 0; l < 4; ++l) {
    gemm_kernel<1><<<dim3(64, 18, 1), 256, 0, stream>>>(
        hbf, WTqkv + (size_t)l * 2304 * 768, bqkv + l * 2304, qkvb, nullptr, 2304, 768, 768);
    vtrans_kernel<<<dim3(64, 12, 2), 256, 0, stream>>>(qkvb, vtb);
    attn_kernel<<<dim3(64, 12, 2), 256, 0, stream>>>(qkvb, vtb, amask, attnb);
    gemm_kernel<0><<<dim3(64, 6, 2), 256, 0, stream>>>(
        attnb, WTo + (size_t)l * 768 * 768, nullptr, tmp, part1, 768, 768, 384);
    add_ln_kernel<<<8192, 256, 0, stream>>>(h32, tmp, part1, bo + l * 768,
                                            ln1g + l * 768, ln1b + l * 768, hbf);
    gemm_kernel<2><<<dim3(64, 24, 1), 256, 0, stream>>>(
        hbf, WTi + (size_t)l * 3072 * 768, bi + l * 3072, ffn1, nullptr, 3072, 768, 768);
    gemm_kernel<0><<<dim3(64, 6, 2), 256, 0, stream>>>(
        ffn1, WTf + (size_t)l * 768 * 3072, nullptr, tmp, part1, 768, 3072, 1536);
    add_ln_kernel<<<8192, 256, 0, stream>>>(h32, tmp, part1, bfb + l * 768,
                                            ln2g + l * 768, ln2b + l * 768, hbf);
  }

  final_kernel<<<2048, 256, 0, stream>>>(h32, Wp, bp, out);
}

// Round 4
// 1502.121 us; speedup vs baseline: 1.0278x; 1.0203x over previous
//
#include <hip/hip_runtime.h>
#include <hip/hip_bf16.h>

// ---------------------------------------------------------------------------
// Longformer-style forward: B=2, S=4096, HID=768, L=4, H=12, D=64, W=128
// R4: double-buffered GEMM k-loop (one barrier/iter; vmcnt drain overlapped
//     with compute), rcp-based divisions in all epilogues (div sequence was
//     ~12 VALU ops each without fast-math).
// ---------------------------------------------------------------------------

typedef __bf16 bf16;
typedef bf16  bf16x8  __attribute__((ext_vector_type(8)));
typedef float floatx4 __attribute__((ext_vector_type(4)));

#define MFMA16(a, b, c) __builtin_amdgcn_mfma_f32_16x16x32_bf16((a), (b), (c), 0, 0, 0)

__device__ __forceinline__ void gld_lds16(const bf16* gp, bf16* lp) {
  __builtin_amdgcn_global_load_lds(
      (const __attribute__((address_space(1))) void*)gp,
      (__attribute__((address_space(3))) void*)lp, 16, 0, 0);
}

__device__ __forceinline__ float fast_rcp(float x) {
  return __builtin_amdgcn_rcpf(x);
}

__device__ __forceinline__ float gelu_tanh(float v) {
  float t = 0.7978845608028654f * (v + 0.044715f * v * v * v);
  float e = __expf(2.f * t);
  float th = 1.f - 2.f * fast_rcp(e + 1.f);
  return 0.5f * v * (1.f + th);
}

// ------------------------- workspace layout (bytes) ------------------------
static constexpr size_t SZ_WTQKV = (size_t)4 * 2304 * 768 * 2;
static constexpr size_t SZ_WTO   = (size_t)4 * 768 * 768 * 2;
static constexpr size_t SZ_WTI   = (size_t)4 * 3072 * 768 * 2;
static constexpr size_t SZ_WTF   = (size_t)4 * 768 * 3072 * 2;
static constexpr size_t SZ_BQKV  = (size_t)4 * 2304 * 4;
static constexpr size_t SZ_H32   = (size_t)8192 * 768 * 4;
static constexpr size_t SZ_HBF   = (size_t)8192 * 768 * 2;
static constexpr size_t SZ_QKV   = (size_t)8192 * 2304 * 2;
static constexpr size_t SZ_ATTN  = (size_t)8192 * 768 * 2;
static constexpr size_t SZ_TMP   = (size_t)8192 * 768 * 4;   // also holds Vt (12.6MB)

static constexpr size_t OFF_WTQKV = 0;
static constexpr size_t OFF_WTO   = OFF_WTQKV + SZ_WTQKV;
static constexpr size_t OFF_WTI   = OFF_WTO   + SZ_WTO;
static constexpr size_t OFF_WTF   = OFF_WTI   + SZ_WTI;
static constexpr size_t OFF_BQKV  = OFF_WTF   + SZ_WTF;
static constexpr size_t OFF_H32   = OFF_BQKV  + SZ_BQKV;
static constexpr size_t OFF_HBF   = OFF_H32   + SZ_H32;
static constexpr size_t OFF_QKV   = OFF_HBF   + SZ_HBF;
static constexpr size_t OFF_ATTN  = OFF_QKV   + SZ_QKV;
static constexpr size_t OFF_TMP   = OFF_ATTN  + SZ_ATTN;
static constexpr size_t OFF_FFN1  = OFF_TMP   + SZ_TMP;

// ------------------------- weight transpose + cast -------------------------
__global__ __launch_bounds__(256) void transpose_cast(
    const float* __restrict__ src, bf16* __restrict__ dst,
    int K, int N, long sStride, long dStride) {
  __shared__ float tile[32][33];
  const int l = blockIdx.z;
  src += (long)l * sStride;
  dst += (long)l * dStride;
  const int n0 = blockIdx.x * 32, k0 = blockIdx.y * 32;
  const int tx = threadIdx.x, ty = threadIdx.y; // (32,8)
#pragma unroll
  for (int i = 0; i < 4; ++i)
    tile[ty + i * 8][tx] = src[(long)(k0 + ty + i * 8) * N + n0 + tx];
  __syncthreads();
#pragma unroll
  for (int i = 0; i < 4; ++i)
    dst[(long)(n0 + ty + i * 8) * K + k0 + tx] = (bf16)tile[tx][ty + i * 8];
}

__global__ void bias_concat(const float* __restrict__ bq, const float* __restrict__ bk,
                            const float* __restrict__ bv, float* __restrict__ bqkv) {
  int i = blockIdx.x * 256 + threadIdx.x; // 4*2304
  if (i >= 4 * 2304) return;
  int l = i / 2304, p = i % 2304;
  float v = (p < 768) ? bq[l * 768 + p]
          : (p < 1536) ? bk[l * 768 + p - 768] : bv[l * 768 + p - 1536];
  bqkv[i] = v;
}

// ------------------------------ LN helpers ---------------------------------
__device__ __forceinline__ void block_stats(float s1, float s2, float* red,
                                            float& mean, float& inv) {
  const int lane = threadIdx.x & 63, wave = threadIdx.x >> 6;
#pragma unroll
  for (int off = 32; off > 0; off >>= 1) {
    s1 += __shfl_down(s1, off, 64);
    s2 += __shfl_down(s2, off, 64);
  }
  if (lane == 0) { red[wave] = s1; red[4 + wave] = s2; }
  __syncthreads();
  s1 = red[0] + red[1] + red[2] + red[3];
  s2 = red[4] + red[5] + red[6] + red[7];
  mean = s1 * (1.f / 768.f);
  float var = s2 * (1.f / 768.f) - mean * mean;
  inv = rsqrtf(var + 1e-12f);
}

__global__ __launch_bounds__(256) void embed_ln_kernel(
    const float* __restrict__ emb, const float* __restrict__ pos,
    const float* __restrict__ tok, const float* __restrict__ g,
    const float* __restrict__ bta, float* __restrict__ h32, bf16* __restrict__ hbf) {
  __shared__ float red[8];
  const long base = (long)blockIdx.x * 768;
  const int s = blockIdx.x & 4095;
  const int t = threadIdx.x;
  float x[3], s1 = 0.f, s2 = 0.f;
#pragma unroll
  for (int i = 0; i < 3; ++i) {
    int c = t + i * 256;
    float v = emb[base + c] + pos[(long)(s + 1) * 768 + c] + tok[c];
    x[i] = v; s1 += v; s2 += v * v;
  }
  float mean, inv;
  block_stats(s1, s2, red, mean, inv);
#pragma unroll
  for (int i = 0; i < 3; ++i) {
    int c = t + i * 256;
    float y = (x[i] - mean) * inv * g[c] + bta[c];
    h32[base + c] = y;
    hbf[base + c] = (bf16)y;
  }
}

__global__ __launch_bounds__(256) void add_ln_kernel(
    float* __restrict__ h32, const float* __restrict__ p0,
    const float* __restrict__ p1, const float* __restrict__ bias,
    const float* __restrict__ g, const float* __restrict__ bta,
    bf16* __restrict__ hbf) {
  __shared__ float red[8];
  const long base = (long)blockIdx.x * 768;
  const int t = threadIdx.x;
  float x[3], s1 = 0.f, s2 = 0.f;
#pragma unroll
  for (int i = 0; i < 3; ++i) {
    int c = t + i * 256;
    float v = h32[base + c] + p0[base + c] + p1[base + c] + bias[c];
    x[i] = v; s1 += v; s2 += v * v;
  }
  float mean, inv;
  block_stats(s1, s2, red, mean, inv);
#pragma unroll
  for (int i = 0; i < 3; ++i) {
    int c = t + i * 256;
    float y = (x[i] - mean) * inv * g[c] + bta[c];
    h32[base + c] = y;
    hbf[base + c] = (bf16)y;
  }
}

// ------------------------------- GEMM --------------------------------------
// m-major grid (id%8 = x%8 -> one A-slab per XCD). Double-buffered k-loop:
// stage tile k+1 into the other 32KB buffer right after the barrier, compute
// tile k, one barrier per iter (its vmcnt(0) drain lands after compute).
// MODE: 0=fp32 partial (split-K via z, no bias), 1=bf16+bias, 2=+tanh-GELU.
template <int MODE>
__global__ __launch_bounds__(256) void gemm_kernel(
    const bf16* __restrict__ A, const bf16* __restrict__ BT,
    const float* __restrict__ bias, void* __restrict__ C0, void* __restrict__ C1,
    int N, int ld, int ksize) {
  __shared__ bf16 As[2][128 * 64];
  __shared__ bf16 Bs[2][128 * 64];
  const int tid  = threadIdx.x;
  const int wave = tid >> 6, lane = tid & 63, l15 = lane & 15, quad = lane >> 4;
  const int wm = wave >> 1, wn = wave & 1;
  const long m0 = (long)blockIdx.x * 128;
  const int  n0 = blockIdx.y * 128;
  const int  k0 = blockIdx.z * ksize;

  floatx4 acc[4][4] = {};
  const bf16* Ag = A + m0 * ld + k0;
  const bf16* Bg = BT + (long)n0 * ld + k0;
  const int rowoff = tid >> 3, sc = tid & 7;

  auto stage = [&](int kt, bf16* Asb, bf16* Bsb) {
#pragma unroll
    for (int p = 0; p < 4; ++p) {
      const int row = p * 32 + rowoff;
      gld_lds16(Ag + (long)row * ld + kt + sc * 8, Asb + p * 2048 + wave * 512);
      gld_lds16(Bg + (long)row * ld + kt + sc * 8, Bsb + p * 2048 + wave * 512);
    }
  };

  stage(0, As[0], Bs[0]);
  int cur = 0;
  for (int kt = 0; kt < ksize; kt += 64) {
    __syncthreads();                 // buf[cur] staged (drains vmcnt here)
    if (kt + 64 < ksize) stage(kt + 64, As[cur ^ 1], Bs[cur ^ 1]);
#pragma unroll
    for (int kk = 0; kk < 2; ++kk) {
      const int ko = kk * 32 + quad * 8;
      bf16x8 af[4], bfr[4];
#pragma unroll
      for (int mt = 0; mt < 4; ++mt)
        af[mt] = *(const bf16x8*)&As[cur][(wm * 64 + mt * 16 + l15) * 64 + ko];
#pragma unroll
      for (int nt = 0; nt < 4; ++nt)
        bfr[nt] = *(const bf16x8*)&Bs[cur][(wn * 64 + nt * 16 + l15) * 64 + ko];
#pragma unroll
      for (int mt = 0; mt < 4; ++mt)
#pragma unroll
        for (int nt = 0; nt < 4; ++nt)
          acc[mt][nt] = MFMA16(af[mt], bfr[nt], acc[mt][nt]);
    }
    cur ^= 1;
  }

  float* Cp32 = (MODE == 0) ? ((blockIdx.z == 0) ? (float*)C0 : (float*)C1) : nullptr;
#pragma unroll
  for (int nt = 0; nt < 4; ++nt) {
    const int col = n0 + wn * 64 + nt * 16 + l15;
    const float bb = (MODE == 0) ? 0.f : bias[col];
#pragma unroll
    for (int mt = 0; mt < 4; ++mt) {
      const long row = m0 + wm * 64 + mt * 16 + quad * 4;
#pragma unroll
      for (int r = 0; r < 4; ++r) {
        float v = acc[mt][nt][r] + bb;
        if (MODE == 2) v = gelu_tanh(v);
        if (MODE == 0) Cp32[(row + r) * N + col] = v;
        else           ((bf16*)C0)[(row + r) * N + col] = (bf16)v;
      }
    }
  }
}

// -------------------- V transpose: qkv V-part -> Vt[b,h][d][S] -------------
__global__ __launch_bounds__(256) void vtrans_kernel(
    const bf16* __restrict__ qkv, bf16* __restrict__ vt) {
  __shared__ bf16 tile[64 * 68];
  const int s0 = blockIdx.x * 64, h = blockIdx.y, b = blockIdx.z;
  const int tid = threadIdx.x;
  const bf16* src = qkv + (long)b * 4096 * 2304 + 1536 + h * 64;
#pragma unroll
  for (int p = 0; p < 2; ++p) {
    const int i = p * 256 + tid;
    const int r = i >> 3, c = i & 7;
    *(uint4*)&tile[r * 68 + c * 8] = *(const uint4*)&src[(long)(s0 + r) * 2304 + c * 8];
  }
  __syncthreads();
  bf16* dst = vt + ((long)(b * 12 + h)) * 64 * 4096;
#pragma unroll
  for (int p = 0; p < 2; ++p) {
    const int i = p * 256 + tid;
    const int d = i >> 3, cs = i & 7;
    bf16 vals[8];
#pragma unroll
    for (int u = 0; u < 8; ++u) vals[u] = tile[(cs * 8 + u) * 68 + d];
    *(uint4*)&dst[(long)d * 4096 + s0 + cs * 8] = *(const uint4*)vals;
  }
}

// ----------------------------- attention -----------------------------------
__global__ __launch_bounds__(256) void attn_kernel(
    const bf16* __restrict__ qkv, const bf16* __restrict__ vt,
    const int* __restrict__ amask, bf16* __restrict__ attn_out) {
  constexpr int S = 4096, HID3 = 2304;
  __shared__ bf16 Ss[64 * 328];
  __shared__ bf16 Ts[64 * 64];
  __shared__ float redm[64], reds[64];

  const int x = blockIdx.x, q0 = x * 64, h = blockIdx.y, b = blockIdx.z;
  const int tid = threadIdx.x, wave = tid >> 6, lane = tid & 63;
  const int l15 = lane & 15, quad = lane >> 4;
  const int rowoff = tid >> 3, sc = tid & 7;
  const int t_lo = (x < 2) ? (2 - x) : 0;
  const int t_hi = (x > 61) ? (66 - x) : 5;

  const bf16* Qb = qkv + (long)b * S * HID3 + h * 64;
  const bf16* Kb = Qb + 768;
  const bf16* Vt_bh = vt + ((long)(b * 12 + h)) * 64 * 4096;

  bf16x8 qf[2];
  {
    const long qrow = q0 + wave * 16 + l15;
    qf[0] = *(const bf16x8*)&Qb[qrow * HID3 + quad * 8];
    qf[1] = *(const bf16x8*)&Qb[qrow * HID3 + 32 + quad * 8];
  }

  float mrow[4] = {-3e38f, -3e38f, -3e38f, -3e38f};

  // ---- Phase A: scores ----
  for (int t = t_lo; t < t_hi; ++t) {
    const int j0 = (x - 2 + t) * 64;
    __syncthreads();
#pragma unroll
    for (int p = 0; p < 2; ++p) {
      const int key = p * 32 + rowoff;
      gld_lds16(Kb + (long)(j0 + key) * HID3 + sc * 8, &Ts[p * 2048 + wave * 512]);
    }
    __syncthreads();
    floatx4 sacc[4] = {};
#pragma unroll
    for (int kk = 0; kk < 2; ++kk) {
      const int ko = kk * 32 + quad * 8;
#pragma unroll
      for (int nt = 0; nt < 4; ++nt) {
        bf16x8 kf = *(const bf16x8*)&Ts[(nt * 16 + l15) * 64 + ko];
        sacc[nt] = MFMA16(qf[kk], kf, sacc[nt]);
      }
    }
#pragma unroll
    for (int nt = 0; nt < 4; ++nt) {
      const int jj = t * 64 + nt * 16 + l15;
      const int j = j0 + nt * 16 + l15;
      const bool jv = (amask[b * S + j] != 0);
#pragma unroll
      for (int r = 0; r < 4; ++r) {
        const int qi = wave * 16 + quad * 4 + r;
        const bool ok = jv && (jj >= qi) && (jj <= qi + 256);
        const float sv = ok ? sacc[nt][r] * 0.125f : -1e9f;
        mrow[r] = fmaxf(mrow[r], sv);
        Ss[(wave * 16 + quad * 4 + r) * 328 + jj] = (bf16)sv;
      }
    }
  }
#pragma unroll
  for (int off = 1; off < 16; off <<= 1)
#pragma unroll
    for (int r = 0; r < 4; ++r)
      mrow[r] = fmaxf(mrow[r], __shfl_xor(mrow[r], off, 64));
  if (l15 == 0) {
#pragma unroll
    for (int r = 0; r < 4; ++r) redm[wave * 16 + quad * 4 + r] = mrow[r];
  }
  __syncthreads();

  // ---- Phase B: softmax pass (rows re-owned by l15, chunks by quad) ----
  {
    const int row = wave * 16 + l15;
    const float mx = redm[row];
    float sum = 0.f;
    for (int c = t_lo * 8 + quad; c < t_hi * 8; c += 4) {
      bf16x8 pv = *(const bf16x8*)&Ss[row * 328 + c * 8];
#pragma unroll
      for (int u = 0; u < 8; ++u) {
        const float p = __expf((float)pv[u] - mx);
        sum += p;
        pv[u] = (bf16)p;
      }
      *(bf16x8*)&Ss[row * 328 + c * 8] = pv;
    }
    sum += __shfl_xor(sum, 16, 64);
    sum += __shfl_xor(sum, 32, 64);
    if (quad == 0) reds[row] = sum;
  }
  __syncthreads();

  // ---- Phase C: P @ V with pre-transposed V ----
  floatx4 oacc[4] = {};
  for (int t = t_lo; t < t_hi; ++t) {
    const int j0 = (x - 2 + t) * 64;
    __syncthreads();
#pragma unroll
    for (int p = 0; p < 2; ++p) {
      const int d = p * 32 + rowoff;
      gld_lds16(Vt_bh + (long)d * 4096 + j0 + sc * 8, &Ts[p * 2048 + wave * 512]);
    }
    __syncthreads();
#pragma unroll
    for (int kk = 0; kk < 2; ++kk) {
      const int ko = kk * 32 + quad * 8;
      bf16x8 pf = *(const bf16x8*)&Ss[(wave * 16 + l15) * 328 + t * 64 + ko];
#pragma unroll
      for (int nt = 0; nt < 4; ++nt) {
        bf16x8 vf = *(const bf16x8*)&Ts[(nt * 16 + l15) * 64 + ko];
        oacc[nt] = MFMA16(pf, vf, oacc[nt]);
      }
    }
  }

  float inv[4];
#pragma unroll
  for (int r = 0; r < 4; ++r) inv[r] = fast_rcp(reds[wave * 16 + quad * 4 + r]);
  const long orow = (long)b * S + q0 + wave * 16 + quad * 4;
#pragma unroll
  for (int nt = 0; nt < 4; ++nt)
#pragma unroll
    for (int r = 0; r < 4; ++r)
      attn_out[(orow + r) * 768 + h * 64 + nt * 16 + l15] =
          (bf16)(oacc[nt][r] * inv[r]);
}

// ------------------------------ final head ---------------------------------
__global__ __launch_bounds__(256) void final_kernel(
    const float* __restrict__ h32, const float* __restrict__ Wp,
    const float* __restrict__ bp, float* __restrict__ out) {
  const int wave = threadIdx.x >> 6, lane = threadIdx.x & 63;
  const long tok = (long)blockIdx.x * 4 + wave;
  float s = 0.f;
#pragma unroll
  for (int i = 0; i < 12; ++i) {
    const int c = lane + i * 64;
    s += h32[tok * 768 + c] * Wp[c];
  }
#pragma unroll
  for (int off = 32; off > 0; off >>= 1) s += __shfl_down(s, off, 64);
  if (lane == 0) out[tok] = fast_rcp(1.f + __expf(-(s + bp[0])));
}

// ------------------------------ launcher -----------------------------------
extern "C" void kernel_launch(void* const* d_in, const int* in_sizes, int n_in,
                              void* d_out, int out_size, void* d_ws, size_t ws_size,
                              hipStream_t stream) {
  const float* emb   = (const float*)d_in[0];
  const int*   amask = (const int*)d_in[1];
  const float* pos   = (const float*)d_in[2];
  const float* tok   = (const float*)d_in[3];
  const float* elng  = (const float*)d_in[4];
  const float* elnb  = (const float*)d_in[5];
  const float* Wq = (const float*)d_in[6];   const float* bq = (const float*)d_in[7];
  const float* Wk = (const float*)d_in[8];   const float* bk = (const float*)d_in[9];
  const float* Wv = (const float*)d_in[10];  const float* bv = (const float*)d_in[11];
  const float* Wo = (const float*)d_in[12];  const float* bo = (const float*)d_in[13];
  const float* ln1g = (const float*)d_in[14]; const float* ln1b = (const float*)d_in[15];
  const float* Wi = (const float*)d_in[16];  const float* bi = (const float*)d_in[17];
  const float* Wf = (const float*)d_in[18];  const float* bfb = (const float*)d_in[19];
  const float* ln2g = (const float*)d_in[20]; const float* ln2b = (const float*)d_in[21];
  const float* Wp = (const float*)d_in[22];  const float* bp = (const float*)d_in[23];
  float* out = (float*)d_out;

  char* ws = (char*)d_ws;
  bf16*  WTqkv = (bf16*)(ws + OFF_WTQKV);
  bf16*  WTo   = (bf16*)(ws + OFF_WTO);
  bf16*  WTi   = (bf16*)(ws + OFF_WTI);
  bf16*  WTf   = (bf16*)(ws + OFF_WTF);
  float* bqkv  = (float*)(ws + OFF_BQKV);
  float* h32   = (float*)(ws + OFF_H32);
  bf16*  hbf   = (bf16*)(ws + OFF_HBF);
  bf16*  qkvb  = (bf16*)(ws + OFF_QKV);
  float* part1 = (float*)(ws + OFF_QKV);   // fp32 overlay; qkvb dead after attn
  bf16*  attnb = (bf16*)(ws + OFF_ATTN);
  float* tmp   = (float*)(ws + OFF_TMP);
  bf16*  vtb   = (bf16*)(ws + OFF_TMP);    // Vt overlay; tmp dead during attn
  bf16*  ffn1  = (bf16*)(ws + OFF_FFN1);

  const dim3 tb(32, 8, 1);
  transpose_cast<<<dim3(24, 24, 4), tb, 0, stream>>>(Wq, WTqkv,               768, 768,  (long)768 * 768,  (long)2304 * 768);
  transpose_cast<<<dim3(24, 24, 4), tb, 0, stream>>>(Wk, WTqkv + 768 * 768,   768, 768,  (long)768 * 768,  (long)2304 * 768);
  transpose_cast<<<dim3(24, 24, 4), tb, 0, stream>>>(Wv, WTqkv + 1536 * 768,  768, 768,  (long)768 * 768,  (long)2304 * 768);
  transpose_cast<<<dim3(24, 24, 4), tb, 0, stream>>>(Wo, WTo,                 768, 768,  (long)768 * 768,  (long)768 * 768);
  transpose_cast<<<dim3(96, 24, 4), tb, 0, stream>>>(Wi, WTi,                 768, 3072, (long)768 * 3072, (long)3072 * 768);
  transpose_cast<<<dim3(24, 96, 4), tb, 0, stream>>>(Wf, WTf,                 3072, 768, (long)3072 * 768, (long)768 * 3072);
  bias_concat<<<36, 256, 0, stream>>>(bq, bk, bv, bqkv);

  embed_ln_kernel<<<8192, 256, 0, stream>>>(emb, pos, tok, elng, elnb, h32, hbf);

  for (int l = 0; l < 4; ++l) {
    gemm_kernel<1><<<dim3(64, 18, 1), 256, 0, stream>>>(
        hbf, WTqkv + (size_t)l * 2304 * 768, bqkv + l * 2304, qkvb, nullptr, 2304, 768, 768);
    vtrans_kernel<<<dim3(64, 12, 2), 256, 0, stream>>>(qkvb, vtb);
    attn_kernel<<<dim3(64, 12, 2), 256, 0, stream>>>(qkvb, vtb, amask, attnb);
    gemm_kernel<0><<<dim3(64, 6, 2), 256, 0, stream>>>(
        attnb, WTo + (size_t)l * 768 * 768, nullptr, tmp, part1, 768, 768, 384);
    add_ln_kernel<<<8192, 256, 0, stream>>>(h32, tmp, part1, bo + l * 768,
                                            ln1g + l * 768, ln1b + l * 768, hbf);
    gemm_kernel<2><<<dim3(64, 24, 1), 256, 0, stream>>>(
        hbf, WTi + (size_t)l * 3072 * 768, bi + l * 3072, ffn1, nullptr, 3072, 768, 768);
    gemm_kernel<0><<<dim3(64, 6, 2), 256, 0, stream>>>(
        ffn1, WTf + (size_t)l * 768 * 3072, nullptr, tmp, part1, 768, 3072, 1536);
    add_ln_kernel<<<8192, 256, 0, stream>>>(h32, tmp, part1, bfb + l * 768,
                                            ln2g + l * 768, ln2b + l * 768, hbf);
  }

  final_kernel<<<2048, 256, 0, stream>>>(h32, Wp, bp, out);
}

// Round 5
// 1359.969 us; speedup vs baseline: 1.1352x; 1.1045x over previous
//
#include <hip/hip_runtime.h>
#include <hip/hip_bf16.h>

// ---------------------------------------------------------------------------
// Longformer-style forward: B=2, S=4096, HID=768, L=4, H=12, D=64, W=128
// R5: XOR-swizzled LDS tiles. Stride-64-bf16 tiles put all 16 lanes of a quad
//     on the same 4 banks (16-way conflict, 12 extra cyc per ds_read_b128,
//     SQ_LDS_BANK_CONFLICT=1.4e7). Swizzle: physical chunk = logical ^ (row&7),
//     staging reads global chunk (tid&7)^((tid>>3)&7) so global_load_lds's
//     lane-contiguous LDS writes land swizzled. Applied to GEMM As/Bs and
//     attention K/V tiles.
// ---------------------------------------------------------------------------

typedef __bf16 bf16;
typedef bf16  bf16x8  __attribute__((ext_vector_type(8)));
typedef float floatx4 __attribute__((ext_vector_type(4)));

#define MFMA16(a, b, c) __builtin_amdgcn_mfma_f32_16x16x32_bf16((a), (b), (c), 0, 0, 0)

__device__ __forceinline__ void gld_lds16(const bf16* gp, bf16* lp) {
  __builtin_amdgcn_global_load_lds(
      (const __attribute__((address_space(1))) void*)gp,
      (__attribute__((address_space(3))) void*)lp, 16, 0, 0);
}

__device__ __forceinline__ float fast_rcp(float x) {
  return __builtin_amdgcn_rcpf(x);
}

__device__ __forceinline__ float gelu_tanh(float v) {
  float t = 0.7978845608028654f * (v + 0.044715f * v * v * v);
  float e = __expf(2.f * t);
  float th = 1.f - 2.f * fast_rcp(e + 1.f);
  return 0.5f * v * (1.f + th);
}

// ------------------------- workspace layout (bytes) ------------------------
static constexpr size_t SZ_WTQKV = (size_t)4 * 2304 * 768 * 2;
static constexpr size_t SZ_WTO   = (size_t)4 * 768 * 768 * 2;
static constexpr size_t SZ_WTI   = (size_t)4 * 3072 * 768 * 2;
static constexpr size_t SZ_WTF   = (size_t)4 * 768 * 3072 * 2;
static constexpr size_t SZ_BQKV  = (size_t)4 * 2304 * 4;
static constexpr size_t SZ_H32   = (size_t)8192 * 768 * 4;
static constexpr size_t SZ_HBF   = (size_t)8192 * 768 * 2;
static constexpr size_t SZ_QKV   = (size_t)8192 * 2304 * 2;
static constexpr size_t SZ_ATTN  = (size_t)8192 * 768 * 2;
static constexpr size_t SZ_TMP   = (size_t)8192 * 768 * 4;   // also holds Vt (12.6MB)

static constexpr size_t OFF_WTQKV = 0;
static constexpr size_t OFF_WTO   = OFF_WTQKV + SZ_WTQKV;
static constexpr size_t OFF_WTI   = OFF_WTO   + SZ_WTO;
static constexpr size_t OFF_WTF   = OFF_WTI   + SZ_WTI;
static constexpr size_t OFF_BQKV  = OFF_WTF   + SZ_WTF;
static constexpr size_t OFF_H32   = OFF_BQKV  + SZ_BQKV;
static constexpr size_t OFF_HBF   = OFF_H32   + SZ_H32;
static constexpr size_t OFF_QKV   = OFF_HBF   + SZ_HBF;
static constexpr size_t OFF_ATTN  = OFF_QKV   + SZ_QKV;
static constexpr size_t OFF_TMP   = OFF_ATTN  + SZ_ATTN;
static constexpr size_t OFF_FFN1  = OFF_TMP   + SZ_TMP;

// ------------------------- weight transpose + cast -------------------------
__global__ __launch_bounds__(256) void transpose_cast(
    const float* __restrict__ src, bf16* __restrict__ dst,
    int K, int N, long sStride, long dStride) {
  __shared__ float tile[32][33];
  const int l = blockIdx.z;
  src += (long)l * sStride;
  dst += (long)l * dStride;
  const int n0 = blockIdx.x * 32, k0 = blockIdx.y * 32;
  const int tx = threadIdx.x, ty = threadIdx.y; // (32,8)
#pragma unroll
  for (int i = 0; i < 4; ++i)
    tile[ty + i * 8][tx] = src[(long)(k0 + ty + i * 8) * N + n0 + tx];
  __syncthreads();
#pragma unroll
  for (int i = 0; i < 4; ++i)
    dst[(long)(n0 + ty + i * 8) * K + k0 + tx] = (bf16)tile[tx][ty + i * 8];
}

__global__ void bias_concat(const float* __restrict__ bq, const float* __restrict__ bk,
                            const float* __restrict__ bv, float* __restrict__ bqkv) {
  int i = blockIdx.x * 256 + threadIdx.x; // 4*2304
  if (i >= 4 * 2304) return;
  int l = i / 2304, p = i % 2304;
  float v = (p < 768) ? bq[l * 768 + p]
          : (p < 1536) ? bk[l * 768 + p - 768] : bv[l * 768 + p - 1536];
  bqkv[i] = v;
}

// ------------------------------ LN helpers ---------------------------------
__device__ __forceinline__ void block_stats(float s1, float s2, float* red,
                                            float& mean, float& inv) {
  const int lane = threadIdx.x & 63, wave = threadIdx.x >> 6;
#pragma unroll
  for (int off = 32; off > 0; off >>= 1) {
    s1 += __shfl_down(s1, off, 64);
    s2 += __shfl_down(s2, off, 64);
  }
  if (lane == 0) { red[wave] = s1; red[4 + wave] = s2; }
  __syncthreads();
  s1 = red[0] + red[1] + red[2] + red[3];
  s2 = red[4] + red[5] + red[6] + red[7];
  mean = s1 * (1.f / 768.f);
  float var = s2 * (1.f / 768.f) - mean * mean;
  inv = rsqrtf(var + 1e-12f);
}

__global__ __launch_bounds__(256) void embed_ln_kernel(
    const float* __restrict__ emb, const float* __restrict__ pos,
    const float* __restrict__ tok, const float* __restrict__ g,
    const float* __restrict__ bta, float* __restrict__ h32, bf16* __restrict__ hbf) {
  __shared__ float red[8];
  const long base = (long)blockIdx.x * 768;
  const int s = blockIdx.x & 4095;
  const int t = threadIdx.x;
  float x[3], s1 = 0.f, s2 = 0.f;
#pragma unroll
  for (int i = 0; i < 3; ++i) {
    int c = t + i * 256;
    float v = emb[base + c] + pos[(long)(s + 1) * 768 + c] + tok[c];
    x[i] = v; s1 += v; s2 += v * v;
  }
  float mean, inv;
  block_stats(s1, s2, red, mean, inv);
#pragma unroll
  for (int i = 0; i < 3; ++i) {
    int c = t + i * 256;
    float y = (x[i] - mean) * inv * g[c] + bta[c];
    h32[base + c] = y;
    hbf[base + c] = (bf16)y;
  }
}

__global__ __launch_bounds__(256) void add_ln_kernel(
    float* __restrict__ h32, const float* __restrict__ p0,
    const float* __restrict__ p1, const float* __restrict__ bias,
    const float* __restrict__ g, const float* __restrict__ bta,
    bf16* __restrict__ hbf) {
  __shared__ float red[8];
  const long base = (long)blockIdx.x * 768;
  const int t = threadIdx.x;
  float x[3], s1 = 0.f, s2 = 0.f;
#pragma unroll
  for (int i = 0; i < 3; ++i) {
    int c = t + i * 256;
    float v = h32[base + c] + p0[base + c] + p1[base + c] + bias[c];
    x[i] = v; s1 += v; s2 += v * v;
  }
  float mean, inv;
  block_stats(s1, s2, red, mean, inv);
#pragma unroll
  for (int i = 0; i < 3; ++i) {
    int c = t + i * 256;
    float y = (x[i] - mean) * inv * g[c] + bta[c];
    h32[base + c] = y;
    hbf[base + c] = (bf16)y;
  }
}

// ------------------------------- GEMM --------------------------------------
// m-major grid (id%8 = x%8 -> one A-slab per XCD). Double-buffered k-loop.
// LDS XOR swizzle: physical 16B chunk = logical ^ (row&7).
// MODE: 0=fp32 partial (split-K via z, no bias), 1=bf16+bias, 2=+tanh-GELU.
template <int MODE>
__global__ __launch_bounds__(256) void gemm_kernel(
    const bf16* __restrict__ A, const bf16* __restrict__ BT,
    const float* __restrict__ bias, void* __restrict__ C0, void* __restrict__ C1,
    int N, int ld, int ksize) {
  __shared__ bf16 As[2][128 * 64];
  __shared__ bf16 Bs[2][128 * 64];
  const int tid  = threadIdx.x;
  const int wave = tid >> 6, lane = tid & 63, l15 = lane & 15, quad = lane >> 4;
  const int wm = wave >> 1, wn = wave & 1;
  const long m0 = (long)blockIdx.x * 128;
  const int  n0 = blockIdx.y * 128;
  const int  k0 = blockIdx.z * ksize;

  floatx4 acc[4][4] = {};
  const bf16* Ag = A + m0 * ld + k0;
  const bf16* Bg = BT + (long)n0 * ld + k0;
  const int rowoff = tid >> 3;
  const int sc_sw = (tid & 7) ^ (rowoff & 7);   // swizzled global chunk
  const int fsw = l15 & 7;                       // frag-read swizzle key

  auto stage = [&](int kt, bf16* Asb, bf16* Bsb) {
#pragma unroll
    for (int p = 0; p < 4; ++p) {
      const int row = p * 32 + rowoff;
      gld_lds16(Ag + (long)row * ld + kt + sc_sw * 8, Asb + p * 2048 + wave * 512);
      gld_lds16(Bg + (long)row * ld + kt + sc_sw * 8, Bsb + p * 2048 + wave * 512);
    }
  };

  stage(0, As[0], Bs[0]);
  int cur = 0;
  for (int kt = 0; kt < ksize; kt += 64) {
    __syncthreads();                 // buf[cur] staged (drains vmcnt here)
    if (kt + 64 < ksize) stage(kt + 64, As[cur ^ 1], Bs[cur ^ 1]);
#pragma unroll
    for (int kk = 0; kk < 2; ++kk) {
      const int ch = ((kk * 4 + quad) ^ fsw) * 8;  // swizzled chunk offset
      bf16x8 af[4], bfr[4];
#pragma unroll
      for (int mt = 0; mt < 4; ++mt)
        af[mt] = *(const bf16x8*)&As[cur][(wm * 64 + mt * 16 + l15) * 64 + ch];
#pragma unroll
      for (int nt = 0; nt < 4; ++nt)
        bfr[nt] = *(const bf16x8*)&Bs[cur][(wn * 64 + nt * 16 + l15) * 64 + ch];
#pragma unroll
      for (int mt = 0; mt < 4; ++mt)
#pragma unroll
        for (int nt = 0; nt < 4; ++nt)
          acc[mt][nt] = MFMA16(af[mt], bfr[nt], acc[mt][nt]);
    }
    cur ^= 1;
  }

  float* Cp32 = (MODE == 0) ? ((blockIdx.z == 0) ? (float*)C0 : (float*)C1) : nullptr;
#pragma unroll
  for (int nt = 0; nt < 4; ++nt) {
    const int col = n0 + wn * 64 + nt * 16 + l15;
    const float bb = (MODE == 0) ? 0.f : bias[col];
#pragma unroll
    for (int mt = 0; mt < 4; ++mt) {
      const long row = m0 + wm * 64 + mt * 16 + quad * 4;
#pragma unroll
      for (int r = 0; r < 4; ++r) {
        float v = acc[mt][nt][r] + bb;
        if (MODE == 2) v = gelu_tanh(v);
        if (MODE == 0) Cp32[(row + r) * N + col] = v;
        else           ((bf16*)C0)[(row + r) * N + col] = (bf16)v;
      }
    }
  }
}

// -------------------- V transpose: qkv V-part -> Vt[b,h][d][S] -------------
__global__ __launch_bounds__(256) void vtrans_kernel(
    const bf16* __restrict__ qkv, bf16* __restrict__ vt) {
  __shared__ bf16 tile[64 * 68];
  const int s0 = blockIdx.x * 64, h = blockIdx.y, b = blockIdx.z;
  const int tid = threadIdx.x;
  const bf16* src = qkv + (long)b * 4096 * 2304 + 1536 + h * 64;
#pragma unroll
  for (int p = 0; p < 2; ++p) {
    const int i = p * 256 + tid;
    const int r = i >> 3, c = i & 7;
    *(uint4*)&tile[r * 68 + c * 8] = *(const uint4*)&src[(long)(s0 + r) * 2304 + c * 8];
  }
  __syncthreads();
  bf16* dst = vt + ((long)(b * 12 + h)) * 64 * 4096;
#pragma unroll
  for (int p = 0; p < 2; ++p) {
    const int i = p * 256 + tid;
    const int d = i >> 3, cs = i & 7;
    bf16 vals[8];
#pragma unroll
    for (int u = 0; u < 8; ++u) vals[u] = tile[(cs * 8 + u) * 68 + d];
    *(uint4*)&dst[(long)d * 4096 + s0 + cs * 8] = *(const uint4*)vals;
  }
}

// ----------------------------- attention -----------------------------------
__global__ __launch_bounds__(256) void attn_kernel(
    const bf16* __restrict__ qkv, const bf16* __restrict__ vt,
    const int* __restrict__ amask, bf16* __restrict__ attn_out) {
  constexpr int S = 4096, HID3 = 2304;
  __shared__ bf16 Ss[64 * 328];
  __shared__ bf16 Ts[64 * 64];
  __shared__ float redm[64], reds[64];

  const int x = blockIdx.x, q0 = x * 64, h = blockIdx.y, b = blockIdx.z;
  const int tid = threadIdx.x, wave = tid >> 6, lane = tid & 63;
  const int l15 = lane & 15, quad = lane >> 4;
  const int rowoff = tid >> 3;
  const int sc_sw = (tid & 7) ^ (rowoff & 7);
  const int fsw = l15 & 7;
  const int t_lo = (x < 2) ? (2 - x) : 0;
  const int t_hi = (x > 61) ? (66 - x) : 5;

  const bf16* Qb = qkv + (long)b * S * HID3 + h * 64;
  const bf16* Kb = Qb + 768;
  const bf16* Vt_bh = vt + ((long)(b * 12 + h)) * 64 * 4096;

  bf16x8 qf[2];
  {
    const long qrow = q0 + wave * 16 + l15;
    qf[0] = *(const bf16x8*)&Qb[qrow * HID3 + quad * 8];
    qf[1] = *(const bf16x8*)&Qb[qrow * HID3 + 32 + quad * 8];
  }

  float mrow[4] = {-3e38f, -3e38f, -3e38f, -3e38f};

  // ---- Phase A: scores ----
  for (int t = t_lo; t < t_hi; ++t) {
    const int j0 = (x - 2 + t) * 64;
    __syncthreads();
#pragma unroll
    for (int p = 0; p < 2; ++p) {
      const int key = p * 32 + rowoff;
      gld_lds16(Kb + (long)(j0 + key) * HID3 + sc_sw * 8, &Ts[p * 2048 + wave * 512]);
    }
    __syncthreads();
    floatx4 sacc[4] = {};
#pragma unroll
    for (int kk = 0; kk < 2; ++kk) {
      const int ch = ((kk * 4 + quad) ^ fsw) * 8;
#pragma unroll
      for (int nt = 0; nt < 4; ++nt) {
        bf16x8 kf = *(const bf16x8*)&Ts[(nt * 16 + l15) * 64 + ch];
        sacc[nt] = MFMA16(qf[kk], kf, sacc[nt]);
      }
    }
#pragma unroll
    for (int nt = 0; nt < 4; ++nt) {
      const int jj = t * 64 + nt * 16 + l15;
      const int j = j0 + nt * 16 + l15;
      const bool jv = (amask[b * S + j] != 0);
#pragma unroll
      for (int r = 0; r < 4; ++r) {
        const int qi = wave * 16 + quad * 4 + r;
        const bool ok = jv && (jj >= qi) && (jj <= qi + 256);
        const float sv = ok ? sacc[nt][r] * 0.125f : -1e9f;
        mrow[r] = fmaxf(mrow[r], sv);
        Ss[(wave * 16 + quad * 4 + r) * 328 + jj] = (bf16)sv;
      }
    }
  }
#pragma unroll
  for (int off = 1; off < 16; off <<= 1)
#pragma unroll
    for (int r = 0; r < 4; ++r)
      mrow[r] = fmaxf(mrow[r], __shfl_xor(mrow[r], off, 64));
  if (l15 == 0) {
#pragma unroll
    for (int r = 0; r < 4; ++r) redm[wave * 16 + quad * 4 + r] = mrow[r];
  }
  __syncthreads();

  // ---- Phase B: softmax pass (rows re-owned by l15, chunks by quad) ----
  {
    const int row = wave * 16 + l15;
    const float mx = redm[row];
    float sum = 0.f;
    for (int c = t_lo * 8 + quad; c < t_hi * 8; c += 4) {
      bf16x8 pv = *(const bf16x8*)&Ss[row * 328 + c * 8];
#pragma unroll
      for (int u = 0; u < 8; ++u) {
        const float p = __expf((float)pv[u] - mx);
        sum += p;
        pv[u] = (bf16)p;
      }
      *(bf16x8*)&Ss[row * 328 + c * 8] = pv;
    }
    sum += __shfl_xor(sum, 16, 64);
    sum += __shfl_xor(sum, 32, 64);
    if (quad == 0) reds[row] = sum;
  }
  __syncthreads();

  // ---- Phase C: P @ V with pre-transposed V ----
  floatx4 oacc[4] = {};
  for (int t = t_lo; t < t_hi; ++t) {
    const int j0 = (x - 2 + t) * 64;
    __syncthreads();
#pragma unroll
    for (int p = 0; p < 2; ++p) {
      const int d = p * 32 + rowoff;
      gld_lds16(Vt_bh + (long)d * 4096 + j0 + sc_sw * 8, &Ts[p * 2048 + wave * 512]);
    }
    __syncthreads();
#pragma unroll
    for (int kk = 0; kk < 2; ++kk) {
      const int ko = kk * 32 + quad * 8;
      const int ch = ((kk * 4 + quad) ^ fsw) * 8;
      bf16x8 pf = *(const bf16x8*)&Ss[(wave * 16 + l15) * 328 + t * 64 + ko];
#pragma unroll
      for (int nt = 0; nt < 4; ++nt) {
        bf16x8 vf = *(const bf16x8*)&Ts[(nt * 16 + l15) * 64 + ch];
        oacc[nt] = MFMA16(pf, vf, oacc[nt]);
      }
    }
  }

  float inv[4];
#pragma unroll
  for (int r = 0; r < 4; ++r) inv[r] = fast_rcp(reds[wave * 16 + quad * 4 + r]);
  const long orow = (long)b * S + q0 + wave * 16 + quad * 4;
#pragma unroll
  for (int nt = 0; nt < 4; ++nt)
#pragma unroll
    for (int r = 0; r < 4; ++r)
      attn_out[(orow + r) * 768 + h * 64 + nt * 16 + l15] =
          (bf16)(oacc[nt][r] * inv[r]);
}

// ------------------------------ final head ---------------------------------
__global__ __launch_bounds__(256) void final_kernel(
    const float* __restrict__ h32, const float* __restrict__ Wp,
    const float* __restrict__ bp, float* __restrict__ out) {
  const int wave = threadIdx.x >> 6, lane = threadIdx.x & 63;
  const long tok = (long)blockIdx.x * 4 + wave;
  float s = 0.f;
#pragma unroll
  for (int i = 0; i < 12; ++i) {
    const int c = lane + i * 64;
    s += h32[tok * 768 + c] * Wp[c];
  }
#pragma unroll
  for (int off = 32; off > 0; off >>= 1) s += __shfl_down(s, off, 64);
  if (lane == 0) out[tok] = fast_rcp(1.f + __expf(-(s + bp[0])));
}

// ------------------------------ launcher -----------------------------------
extern "C" void kernel_launch(void* const* d_in, const int* in_sizes, int n_in,
                              void* d_out, int out_size, void* d_ws, size_t ws_size,
                              hipStream_t stream) {
  const float* emb   = (const float*)d_in[0];
  const int*   amask = (const int*)d_in[1];
  const float* pos   = (const float*)d_in[2];
  const float* tok   = (const float*)d_in[3];
  const float* elng  = (const float*)d_in[4];
  const float* elnb  = (const float*)d_in[5];
  const float* Wq = (const float*)d_in[6];   const float* bq = (const float*)d_in[7];
  const float* Wk = (const float*)d_in[8];   const float* bk = (const float*)d_in[9];
  const float* Wv = (const float*)d_in[10];  const float* bv = (const float*)d_in[11];
  const float* Wo = (const float*)d_in[12];  const float* bo = (const float*)d_in[13];
  const float* ln1g = (const float*)d_in[14]; const float* ln1b = (const float*)d_in[15];
  const float* Wi = (const float*)d_in[16];  const float* bi = (const float*)d_in[17];
  const float* Wf = (const float*)d_in[18];  const float* bfb = (const float*)d_in[19];
  const float* ln2g = (const float*)d_in[20]; const float* ln2b = (const float*)d_in[21];
  const float* Wp = (const float*)d_in[22];  const float* bp = (const float*)d_in[23];
  float* out = (float*)d_out;

  char* ws = (char*)d_ws;
  bf16*  WTqkv = (bf16*)(ws + OFF_WTQKV);
  bf16*  WTo   = (bf16*)(ws + OFF_WTO);
  bf16*  WTi   = (bf16*)(ws + OFF_WTI);
  bf16*  WTf   = (bf16*)(ws + OFF_WTF);
  float* bqkv  = (float*)(ws + OFF_BQKV);
  float* h32   = (float*)(ws + OFF_H32);
  bf16*  hbf   = (bf16*)(ws + OFF_HBF);
  bf16*  qkvb  = (bf16*)(ws + OFF_QKV);
  float* part1 = (float*)(ws + OFF_QKV);   // fp32 overlay; qkvb dead after attn
  bf16*  attnb = (bf16*)(ws + OFF_ATTN);
  float* tmp   = (float*)(ws + OFF_TMP);
  bf16*  vtb   = (bf16*)(ws + OFF_TMP);    // Vt overlay; tmp dead during attn
  bf16*  ffn1  = (bf16*)(ws + OFF_FFN1);

  const dim3 tb(32, 8, 1);
  transpose_cast<<<dim3(24, 24, 4), tb, 0, stream>>>(Wq, WTqkv,               768, 768,  (long)768 * 768,  (long)2304 * 768);
  transpose_cast<<<dim3(24, 24, 4), tb, 0, stream>>>(Wk, WTqkv + 768 * 768,   768, 768,  (long)768 * 768,  (long)2304 * 768);
  transpose_cast<<<dim3(24, 24, 4), tb, 0, stream>>>(Wv, WTqkv + 1536 * 768,  768, 768,  (long)768 * 768,  (long)2304 * 768);
  transpose_cast<<<dim3(24, 24, 4), tb, 0, stream>>>(Wo, WTo,                 768, 768,  (long)768 * 768,  (long)768 * 768);
  transpose_cast<<<dim3(96, 24, 4), tb, 0, stream>>>(Wi, WTi,                 768, 3072, (long)768 * 3072, (long)3072 * 768);
  transpose_cast<<<dim3(24, 96, 4), tb, 0, stream>>>(Wf, WTf,                 3072, 768, (long)3072 * 768, (long)768 * 3072);
  bias_concat<<<36, 256, 0, stream>>>(bq, bk, bv, bqkv);

  embed_ln_kernel<<<8192, 256, 0, stream>>>(emb, pos, tok, elng, elnb, h32, hbf);

  for (int l = 0; l < 4; ++l) {
    gemm_kernel<1><<<dim3(64, 18, 1), 256, 0, stream>>>(
        hbf, WTqkv + (size_t)l * 2304 * 768, bqkv + l * 2304, qkvb, nullptr, 2304, 768, 768);
    vtrans_kernel<<<dim3(64, 12, 2), 256, 0, stream>>>(qkvb, vtb);
    attn_kernel<<<dim3(64, 12, 2), 256, 0, stream>>>(qkvb, vtb, amask, attnb);
    gemm_kernel<0><<<dim3(64, 6, 2), 256, 0, stream>>>(
        attnb, WTo + (size_t)l * 768 * 768, nullptr, tmp, part1, 768, 768, 384);
    add_ln_kernel<<<8192, 256, 0, stream>>>(h32, tmp, part1, bo + l * 768,
                                            ln1g + l * 768, ln1b + l * 768, hbf);
    gemm_kernel<2><<<dim3(64, 24, 1), 256, 0, stream>>>(
        hbf, WTi + (size_t)l * 3072 * 768, bi + l * 3072, ffn1, nullptr, 3072, 768, 768);
    gemm_kernel<0><<<dim3(64, 6, 2), 256, 0, stream>>>(
        ffn1, WTf + (size_t)l * 768 * 3072, nullptr, tmp, part1, 768, 3072, 1536);
    add_ln_kernel<<<8192, 256, 0, stream>>>(h32, tmp, part1, bfb + l * 768,
                                            ln2g + l * 768, ln2b + l * 768, hbf);
  }

  final_kernel<<<2048, 256, 0, stream>>>(h32, Wp, bp, out);
}

// Round 6
// 1283.405 us; speedup vs baseline: 1.2030x; 1.0597x over previous
//
#include <hip/hip_runtime.h>
#include <hip/hip_bf16.h>

// ---------------------------------------------------------------------------
// Longformer-style forward: B=2, S=4096, HID=768, L=4, H=12, D=64, W=128
// R6: single-buffered 32KB GEMM k-loop (m97 2-barrier structure) + swizzle.
//     R4's 64KB double-buffer capped occupancy at 2 blocks/CU; regs allow 3.
//     Swizzle (R5) stays: physical 16B chunk = logical ^ (row&7).
// ---------------------------------------------------------------------------

typedef __bf16 bf16;
typedef bf16  bf16x8  __attribute__((ext_vector_type(8)));
typedef float floatx4 __attribute__((ext_vector_type(4)));

#define MFMA16(a, b, c) __builtin_amdgcn_mfma_f32_16x16x32_bf16((a), (b), (c), 0, 0, 0)

__device__ __forceinline__ void gld_lds16(const bf16* gp, bf16* lp) {
  __builtin_amdgcn_global_load_lds(
      (const __attribute__((address_space(1))) void*)gp,
      (__attribute__((address_space(3))) void*)lp, 16, 0, 0);
}

__device__ __forceinline__ float fast_rcp(float x) {
  return __builtin_amdgcn_rcpf(x);
}

__device__ __forceinline__ float gelu_tanh(float v) {
  float t = 0.7978845608028654f * (v + 0.044715f * v * v * v);
  float e = __expf(2.f * t);
  float th = 1.f - 2.f * fast_rcp(e + 1.f);
  return 0.5f * v * (1.f + th);
}

// ------------------------- workspace layout (bytes) ------------------------
static constexpr size_t SZ_WTQKV = (size_t)4 * 2304 * 768 * 2;
static constexpr size_t SZ_WTO   = (size_t)4 * 768 * 768 * 2;
static constexpr size_t SZ_WTI   = (size_t)4 * 3072 * 768 * 2;
static constexpr size_t SZ_WTF   = (size_t)4 * 768 * 3072 * 2;
static constexpr size_t SZ_BQKV  = (size_t)4 * 2304 * 4;
static constexpr size_t SZ_H32   = (size_t)8192 * 768 * 4;
static constexpr size_t SZ_HBF   = (size_t)8192 * 768 * 2;
static constexpr size_t SZ_QKV   = (size_t)8192 * 2304 * 2;
static constexpr size_t SZ_ATTN  = (size_t)8192 * 768 * 2;
static constexpr size_t SZ_TMP   = (size_t)8192 * 768 * 4;   // also holds Vt (12.6MB)

static constexpr size_t OFF_WTQKV = 0;
static constexpr size_t OFF_WTO   = OFF_WTQKV + SZ_WTQKV;
static constexpr size_t OFF_WTI   = OFF_WTO   + SZ_WTO;
static constexpr size_t OFF_WTF   = OFF_WTI   + SZ_WTI;
static constexpr size_t OFF_BQKV  = OFF_WTF   + SZ_WTF;
static constexpr size_t OFF_H32   = OFF_BQKV  + SZ_BQKV;
static constexpr size_t OFF_HBF   = OFF_H32   + SZ_H32;
static constexpr size_t OFF_QKV   = OFF_HBF   + SZ_HBF;
static constexpr size_t OFF_ATTN  = OFF_QKV   + SZ_QKV;
static constexpr size_t OFF_TMP   = OFF_ATTN  + SZ_ATTN;
static constexpr size_t OFF_FFN1  = OFF_TMP   + SZ_TMP;

// ------------------------- weight transpose + cast -------------------------
__global__ __launch_bounds__(256) void transpose_cast(
    const float* __restrict__ src, bf16* __restrict__ dst,
    int K, int N, long sStride, long dStride) {
  __shared__ float tile[32][33];
  const int l = blockIdx.z;
  src += (long)l * sStride;
  dst += (long)l * dStride;
  const int n0 = blockIdx.x * 32, k0 = blockIdx.y * 32;
  const int tx = threadIdx.x, ty = threadIdx.y; // (32,8)
#pragma unroll
  for (int i = 0; i < 4; ++i)
    tile[ty + i * 8][tx] = src[(long)(k0 + ty + i * 8) * N + n0 + tx];
  __syncthreads();
#pragma unroll
  for (int i = 0; i < 4; ++i)
    dst[(long)(n0 + ty + i * 8) * K + k0 + tx] = (bf16)tile[tx][ty + i * 8];
}

__global__ void bias_concat(const float* __restrict__ bq, const float* __restrict__ bk,
                            const float* __restrict__ bv, float* __restrict__ bqkv) {
  int i = blockIdx.x * 256 + threadIdx.x; // 4*2304
  if (i >= 4 * 2304) return;
  int l = i / 2304, p = i % 2304;
  float v = (p < 768) ? bq[l * 768 + p]
          : (p < 1536) ? bk[l * 768 + p - 768] : bv[l * 768 + p - 1536];
  bqkv[i] = v;
}

// ------------------------------ LN helpers ---------------------------------
__device__ __forceinline__ void block_stats(float s1, float s2, float* red,
                                            float& mean, float& inv) {
  const int lane = threadIdx.x & 63, wave = threadIdx.x >> 6;
#pragma unroll
  for (int off = 32; off > 0; off >>= 1) {
    s1 += __shfl_down(s1, off, 64);
    s2 += __shfl_down(s2, off, 64);
  }
  if (lane == 0) { red[wave] = s1; red[4 + wave] = s2; }
  __syncthreads();
  s1 = red[0] + red[1] + red[2] + red[3];
  s2 = red[4] + red[5] + red[6] + red[7];
  mean = s1 * (1.f / 768.f);
  float var = s2 * (1.f / 768.f) - mean * mean;
  inv = rsqrtf(var + 1e-12f);
}

__global__ __launch_bounds__(256) void embed_ln_kernel(
    const float* __restrict__ emb, const float* __restrict__ pos,
    const float* __restrict__ tok, const float* __restrict__ g,
    const float* __restrict__ bta, float* __restrict__ h32, bf16* __restrict__ hbf) {
  __shared__ float red[8];
  const long base = (long)blockIdx.x * 768;
  const int s = blockIdx.x & 4095;
  const int t = threadIdx.x;
  float x[3], s1 = 0.f, s2 = 0.f;
#pragma unroll
  for (int i = 0; i < 3; ++i) {
    int c = t + i * 256;
    float v = emb[base + c] + pos[(long)(s + 1) * 768 + c] + tok[c];
    x[i] = v; s1 += v; s2 += v * v;
  }
  float mean, inv;
  block_stats(s1, s2, red, mean, inv);
#pragma unroll
  for (int i = 0; i < 3; ++i) {
    int c = t + i * 256;
    float y = (x[i] - mean) * inv * g[c] + bta[c];
    h32[base + c] = y;
    hbf[base + c] = (bf16)y;
  }
}

__global__ __launch_bounds__(256) void add_ln_kernel(
    float* __restrict__ h32, const float* __restrict__ p0,
    const float* __restrict__ p1, const float* __restrict__ bias,
    const float* __restrict__ g, const float* __restrict__ bta,
    bf16* __restrict__ hbf) {
  __shared__ float red[8];
  const long base = (long)blockIdx.x * 768;
  const int t = threadIdx.x;
  float x[3], s1 = 0.f, s2 = 0.f;
#pragma unroll
  for (int i = 0; i < 3; ++i) {
    int c = t + i * 256;
    float v = h32[base + c] + p0[base + c] + p1[base + c] + bias[c];
    x[i] = v; s1 += v; s2 += v * v;
  }
  float mean, inv;
  block_stats(s1, s2, red, mean, inv);
#pragma unroll
  for (int i = 0; i < 3; ++i) {
    int c = t + i * 256;
    float y = (x[i] - mean) * inv * g[c] + bta[c];
    h32[base + c] = y;
    hbf[base + c] = (bf16)y;
  }
}

// ------------------------------- GEMM --------------------------------------
// m-major grid (id%8 = x%8 -> one A-slab per XCD). Single-buffered 32KB k-loop
// (m97 2-barrier structure; 3 blocks/CU by regs). LDS XOR swizzle: physical
// 16B chunk = logical ^ (row&7).
// MODE: 0=fp32 partial (split-K via z, no bias), 1=bf16+bias, 2=+tanh-GELU.
template <int MODE>
__global__ __launch_bounds__(256) void gemm_kernel(
    const bf16* __restrict__ A, const bf16* __restrict__ BT,
    const float* __restrict__ bias, void* __restrict__ C0, void* __restrict__ C1,
    int N, int ld, int ksize) {
  __shared__ bf16 As[128 * 64];
  __shared__ bf16 Bs[128 * 64];
  const int tid  = threadIdx.x;
  const int wave = tid >> 6, lane = tid & 63, l15 = lane & 15, quad = lane >> 4;
  const int wm = wave >> 1, wn = wave & 1;
  const long m0 = (long)blockIdx.x * 128;
  const int  n0 = blockIdx.y * 128;
  const int  k0 = blockIdx.z * ksize;

  floatx4 acc[4][4] = {};
  const bf16* Ag = A + m0 * ld + k0;
  const bf16* Bg = BT + (long)n0 * ld + k0;
  const int rowoff = tid >> 3;
  const int sc_sw = (tid & 7) ^ (rowoff & 7);   // swizzled global chunk
  const int fsw = l15 & 7;                       // frag-read swizzle key

  for (int kt = 0; kt < ksize; kt += 64) {
#pragma unroll
    for (int p = 0; p < 4; ++p) {
      const int row = p * 32 + rowoff;
      gld_lds16(Ag + (long)row * ld + kt + sc_sw * 8, As + p * 2048 + wave * 512);
      gld_lds16(Bg + (long)row * ld + kt + sc_sw * 8, Bs + p * 2048 + wave * 512);
    }
    __syncthreads();
#pragma unroll
    for (int kk = 0; kk < 2; ++kk) {
      const int ch = ((kk * 4 + quad) ^ fsw) * 8;  // swizzled chunk offset
      bf16x8 af[4], bfr[4];
#pragma unroll
      for (int mt = 0; mt < 4; ++mt)
        af[mt] = *(const bf16x8*)&As[(wm * 64 + mt * 16 + l15) * 64 + ch];
#pragma unroll
      for (int nt = 0; nt < 4; ++nt)
        bfr[nt] = *(const bf16x8*)&Bs[(wn * 64 + nt * 16 + l15) * 64 + ch];
#pragma unroll
      for (int mt = 0; mt < 4; ++mt)
#pragma unroll
        for (int nt = 0; nt < 4; ++nt)
          acc[mt][nt] = MFMA16(af[mt], bfr[nt], acc[mt][nt]);
    }
    __syncthreads();
  }

  float* Cp32 = (MODE == 0) ? ((blockIdx.z == 0) ? (float*)C0 : (float*)C1) : nullptr;
#pragma unroll
  for (int nt = 0; nt < 4; ++nt) {
    const int col = n0 + wn * 64 + nt * 16 + l15;
    const float bb = (MODE == 0) ? 0.f : bias[col];
#pragma unroll
    for (int mt = 0; mt < 4; ++mt) {
      const long row = m0 + wm * 64 + mt * 16 + quad * 4;
#pragma unroll
      for (int r = 0; r < 4; ++r) {
        float v = acc[mt][nt][r] + bb;
        if (MODE == 2) v = gelu_tanh(v);
        if (MODE == 0) Cp32[(row + r) * N + col] = v;
        else           ((bf16*)C0)[(row + r) * N + col] = (bf16)v;
      }
    }
  }
}

// -------------------- V transpose: qkv V-part -> Vt[b,h][d][S] -------------
__global__ __launch_bounds__(256) void vtrans_kernel(
    const bf16* __restrict__ qkv, bf16* __restrict__ vt) {
  __shared__ bf16 tile[64 * 68];
  const int s0 = blockIdx.x * 64, h = blockIdx.y, b = blockIdx.z;
  const int tid = threadIdx.x;
  const bf16* src = qkv + (long)b * 4096 * 2304 + 1536 + h * 64;
#pragma unroll
  for (int p = 0; p < 2; ++p) {
    const int i = p * 256 + tid;
    const int r = i >> 3, c = i & 7;
    *(uint4*)&tile[r * 68 + c * 8] = *(const uint4*)&src[(long)(s0 + r) * 2304 + c * 8];
  }
  __syncthreads();
  bf16* dst = vt + ((long)(b * 12 + h)) * 64 * 4096;
#pragma unroll
  for (int p = 0; p < 2; ++p) {
    const int i = p * 256 + tid;
    const int d = i >> 3, cs = i & 7;
    bf16 vals[8];
#pragma unroll
    for (int u = 0; u < 8; ++u) vals[u] = tile[(cs * 8 + u) * 68 + d];
    *(uint4*)&dst[(long)d * 4096 + s0 + cs * 8] = *(const uint4*)vals;
  }
}

// ----------------------------- attention -----------------------------------
__global__ __launch_bounds__(256) void attn_kernel(
    const bf16* __restrict__ qkv, const bf16* __restrict__ vt,
    const int* __restrict__ amask, bf16* __restrict__ attn_out) {
  constexpr int S = 4096, HID3 = 2304;
  __shared__ bf16 Ss[64 * 328];
  __shared__ bf16 Ts[64 * 64];
  __shared__ float redm[64], reds[64];

  const int x = blockIdx.x, q0 = x * 64, h = blockIdx.y, b = blockIdx.z;
  const int tid = threadIdx.x, wave = tid >> 6, lane = tid & 63;
  const int l15 = lane & 15, quad = lane >> 4;
  const int rowoff = tid >> 3;
  const int sc_sw = (tid & 7) ^ (rowoff & 7);
  const int fsw = l15 & 7;
  const int t_lo = (x < 2) ? (2 - x) : 0;
  const int t_hi = (x > 61) ? (66 - x) : 5;

  const bf16* Qb = qkv + (long)b * S * HID3 + h * 64;
  const bf16* Kb = Qb + 768;
  const bf16* Vt_bh = vt + ((long)(b * 12 + h)) * 64 * 4096;

  bf16x8 qf[2];
  {
    const long qrow = q0 + wave * 16 + l15;
    qf[0] = *(const bf16x8*)&Qb[qrow * HID3 + quad * 8];
    qf[1] = *(const bf16x8*)&Qb[qrow * HID3 + 32 + quad * 8];
  }

  float mrow[4] = {-3e38f, -3e38f, -3e38f, -3e38f};

  // ---- Phase A: scores ----
  for (int t = t_lo; t < t_hi; ++t) {
    const int j0 = (x - 2 + t) * 64;
    __syncthreads();
#pragma unroll
    for (int p = 0; p < 2; ++p) {
      const int key = p * 32 + rowoff;
      gld_lds16(Kb + (long)(j0 + key) * HID3 + sc_sw * 8, &Ts[p * 2048 + wave * 512]);
    }
    __syncthreads();
    floatx4 sacc[4] = {};
#pragma unroll
    for (int kk = 0; kk < 2; ++kk) {
      const int ch = ((kk * 4 + quad) ^ fsw) * 8;
#pragma unroll
      for (int nt = 0; nt < 4; ++nt) {
        bf16x8 kf = *(const bf16x8*)&Ts[(nt * 16 + l15) * 64 + ch];
        sacc[nt] = MFMA16(qf[kk], kf, sacc[nt]);
      }
    }
#pragma unroll
    for (int nt = 0; nt < 4; ++nt) {
      const int jj = t * 64 + nt * 16 + l15;
      const int j = j0 + nt * 16 + l15;
      const bool jv = (amask[b * S + j] != 0);
#pragma unroll
      for (int r = 0; r < 4; ++r) {
        const int qi = wave * 16 + quad * 4 + r;
        const bool ok = jv && (jj >= qi) && (jj <= qi + 256);
        const float sv = ok ? sacc[nt][r] * 0.125f : -1e9f;
        mrow[r] = fmaxf(mrow[r], sv);
        Ss[(wave * 16 + quad * 4 + r) * 328 + jj] = (bf16)sv;
      }
    }
  }
#pragma unroll
  for (int off = 1; off < 16; off <<= 1)
#pragma unroll
    for (int r = 0; r < 4; ++r)
      mrow[r] = fmaxf(mrow[r], __shfl_xor(mrow[r], off, 64));
  if (l15 == 0) {
#pragma unroll
    for (int r = 0; r < 4; ++r) redm[wave * 16 + quad * 4 + r] = mrow[r];
  }
  __syncthreads();

  // ---- Phase B: softmax pass (rows re-owned by l15, chunks by quad) ----
  {
    const int row = wave * 16 + l15;
    const float mx = redm[row];
    float sum = 0.f;
    for (int c = t_lo * 8 + quad; c < t_hi * 8; c += 4) {
      bf16x8 pv = *(const bf16x8*)&Ss[row * 328 + c * 8];
#pragma unroll
      for (int u = 0; u < 8; ++u) {
        const float p = __expf((float)pv[u] - mx);
        sum += p;
        pv[u] = (bf16)p;
      }
      *(bf16x8*)&Ss[row * 328 + c * 8] = pv;
    }
    sum += __shfl_xor(sum, 16, 64);
    sum += __shfl_xor(sum, 32, 64);
    if (quad == 0) reds[row] = sum;
  }
  __syncthreads();

  // ---- Phase C: P @ V with pre-transposed V ----
  floatx4 oacc[4] = {};
  for (int t = t_lo; t < t_hi; ++t) {
    const int j0 = (x - 2 + t) * 64;
    __syncthreads();
#pragma unroll
    for (int p = 0; p < 2; ++p) {
      const int d = p * 32 + rowoff;
      gld_lds16(Vt_bh + (long)d * 4096 + j0 + sc_sw * 8, &Ts[p * 2048 + wave * 512]);
    }
    __syncthreads();
#pragma unroll
    for (int kk = 0; kk < 2; ++kk) {
      const int ko = kk * 32 + quad * 8;
      const int ch = ((kk * 4 + quad) ^ fsw) * 8;
      bf16x8 pf = *(const bf16x8*)&Ss[(wave * 16 + l15) * 328 + t * 64 + ko];
#pragma unroll
      for (int nt = 0; nt < 4; ++nt) {
        bf16x8 vf = *(const bf16x8*)&Ts[(nt * 16 + l15) * 64 + ch];
        oacc[nt] = MFMA16(pf, vf, oacc[nt]);
      }
    }
  }

  float inv[4];
#pragma unroll
  for (int r = 0; r < 4; ++r) inv[r] = fast_rcp(reds[wave * 16 + quad * 4 + r]);
  const long orow = (long)b * S + q0 + wave * 16 + quad * 4;
#pragma unroll
  for (int nt = 0; nt < 4; ++nt)
#pragma unroll
    for (int r = 0; r < 4; ++r)
      attn_out[(orow + r) * 768 + h * 64 + nt * 16 + l15] =
          (bf16)(oacc[nt][r] * inv[r]);
}

// ------------------------------ final head ---------------------------------
__global__ __launch_bounds__(256) void final_kernel(
    const float* __restrict__ h32, const float* __restrict__ Wp,
    const float* __restrict__ bp, float* __restrict__ out) {
  const int wave = threadIdx.x >> 6, lane = threadIdx.x & 63;
  const long tok = (long)blockIdx.x * 4 + wave;
  float s = 0.f;
#pragma unroll
  for (int i = 0; i < 12; ++i) {
    const int c = lane + i * 64;
    s += h32[tok * 768 + c] * Wp[c];
  }
#pragma unroll
  for (int off = 32; off > 0; off >>= 1) s += __shfl_down(s, off, 64);
  if (lane == 0) out[tok] = fast_rcp(1.f + __expf(-(s + bp[0])));
}

// ------------------------------ launcher -----------------------------------
extern "C" void kernel_launch(void* const* d_in, const int* in_sizes, int n_in,
                              void* d_out, int out_size, void* d_ws, size_t ws_size,
                              hipStream_t stream) {
  const float* emb   = (const float*)d_in[0];
  const int*   amask = (const int*)d_in[1];
  const float* pos   = (const float*)d_in[2];
  const float* tok   = (const float*)d_in[3];
  const float* elng  = (const float*)d_in[4];
  const float* elnb  = (const float*)d_in[5];
  const float* Wq = (const float*)d_in[6];   const float* bq = (const float*)d_in[7];
  const float* Wk = (const float*)d_in[8];   const float* bk = (const float*)d_in[9];
  const float* Wv = (const float*)d_in[10];  const float* bv = (const float*)d_in[11];
  const float* Wo = (const float*)d_in[12];  const float* bo = (const float*)d_in[13];
  const float* ln1g = (const float*)d_in[14]; const float* ln1b = (const float*)d_in[15];
  const float* Wi = (const float*)d_in[16];  const float* bi = (const float*)d_in[17];
  const float* Wf = (const float*)d_in[18];  const float* bfb = (const float*)d_in[19];
  const float* ln2g = (const float*)d_in[20]; const float* ln2b = (const float*)d_in[21];
  const float* Wp = (const float*)d_in[22];  const float* bp = (const float*)d_in[23];
  float* out = (float*)d_out;

  char* ws = (char*)d_ws;
  bf16*  WTqkv = (bf16*)(ws + OFF_WTQKV);
  bf16*  WTo   = (bf16*)(ws + OFF_WTO);
  bf16*  WTi   = (bf16*)(ws + OFF_WTI);
  bf16*  WTf   = (bf16*)(ws + OFF_WTF);
  float* bqkv  = (float*)(ws + OFF_BQKV);
  float* h32   = (float*)(ws + OFF_H32);
  bf16*  hbf   = (bf16*)(ws + OFF_HBF);
  bf16*  qkvb  = (bf16*)(ws + OFF_QKV);
  float* part1 = (float*)(ws + OFF_QKV);   // fp32 overlay; qkvb dead after attn
  bf16*  attnb = (bf16*)(ws + OFF_ATTN);
  float* tmp   = (float*)(ws + OFF_TMP);
  bf16*  vtb   = (bf16*)(ws + OFF_TMP);    // Vt overlay; tmp dead during attn
  bf16*  ffn1  = (bf16*)(ws + OFF_FFN1);

  const dim3 tb(32, 8, 1);
  transpose_cast<<<dim3(24, 24, 4), tb, 0, stream>>>(Wq, WTqkv,               768, 768,  (long)768 * 768,  (long)2304 * 768);
  transpose_cast<<<dim3(24, 24, 4), tb, 0, stream>>>(Wk, WTqkv + 768 * 768,   768, 768,  (long)768 * 768,  (long)2304 * 768);
  transpose_cast<<<dim3(24, 24, 4), tb, 0, stream>>>(Wv, WTqkv + 1536 * 768,  768, 768,  (long)768 * 768,  (long)2304 * 768);
  transpose_cast<<<dim3(24, 24, 4), tb, 0, stream>>>(Wo, WTo,                 768, 768,  (long)768 * 768,  (long)768 * 768);
  transpose_cast<<<dim3(96, 24, 4), tb, 0, stream>>>(Wi, WTi,                 768, 3072, (long)768 * 3072, (long)3072 * 768);
  transpose_cast<<<dim3(24, 96, 4), tb, 0, stream>>>(Wf, WTf,                 3072, 768, (long)3072 * 768, (long)768 * 3072);
  bias_concat<<<36, 256, 0, stream>>>(bq, bk, bv, bqkv);

  embed_ln_kernel<<<8192, 256, 0, stream>>>(emb, pos, tok, elng, elnb, h32, hbf);

  for (int l = 0; l < 4; ++l) {
    gemm_kernel<1><<<dim3(64, 18, 1), 256, 0, stream>>>(
        hbf, WTqkv + (size_t)l * 2304 * 768, bqkv + l * 2304, qkvb, nullptr, 2304, 768, 768);
    vtrans_kernel<<<dim3(64, 12, 2), 256, 0, stream>>>(qkvb, vtb);
    attn_kernel<<<dim3(64, 12, 2), 256, 0, stream>>>(qkvb, vtb, amask, attnb);
    gemm_kernel<0><<<dim3(64, 6, 2), 256, 0, stream>>>(
        attnb, WTo + (size_t)l * 768 * 768, nullptr, tmp, part1, 768, 768, 384);
    add_ln_kernel<<<8192, 256, 0, stream>>>(h32, tmp, part1, bo + l * 768,
                                            ln1g + l * 768, ln1b + l * 768, hbf);
    gemm_kernel<2><<<dim3(64, 24, 1), 256, 0, stream>>>(
        hbf, WTi + (size_t)l * 3072 * 768, bi + l * 3072, ffn1, nullptr, 3072, 768, 768);
    gemm_kernel<0><<<dim3(64, 6, 2), 256, 0, stream>>>(
        ffn1, WTf + (size_t)l * 768 * 3072, nullptr, tmp, part1, 768, 3072, 1536);
    add_ln_kernel<<<8192, 256, 0, stream>>>(h32, tmp, part1, bfb + l * 768,
                                            ln2g + l * 768, ln2b + l * 768, hbf);
  }

  final_kernel<<<2048, 256, 0, stream>>>(h32, Wp, bp, out);
}

// Round 7
// 1151.163 us; speedup vs baseline: 1.3412x; 1.1149x over previous
//
#include <hip/hip_runtime.h>
#include <hip/hip_bf16.h>

// ---------------------------------------------------------------------------
// Longformer-style forward: B=2, S=4096, HID=768, L=4, H=12, D=64, W=128
// R7: coalesced GEMM epilogue (AGPR -> padded LDS -> bf16x8 row stores; fixes
//     1.7x HBM write amplification from scattered 2B stores) + bf16 split-K
//     partials (halves partial write + add_ln read traffic).
// ---------------------------------------------------------------------------

typedef __bf16 bf16;
typedef bf16  bf16x8  __attribute__((ext_vector_type(8)));
typedef float floatx4 __attribute__((ext_vector_type(4)));

#define MFMA16(a, b, c) __builtin_amdgcn_mfma_f32_16x16x32_bf16((a), (b), (c), 0, 0, 0)

__device__ __forceinline__ void gld_lds16(const bf16* gp, bf16* lp) {
  __builtin_amdgcn_global_load_lds(
      (const __attribute__((address_space(1))) void*)gp,
      (__attribute__((address_space(3))) void*)lp, 16, 0, 0);
}

__device__ __forceinline__ float fast_rcp(float x) {
  return __builtin_amdgcn_rcpf(x);
}

__device__ __forceinline__ float gelu_tanh(float v) {
  float t = 0.7978845608028654f * (v + 0.044715f * v * v * v);
  float e = __expf(2.f * t);
  float th = 1.f - 2.f * fast_rcp(e + 1.f);
  return 0.5f * v * (1.f + th);
}

// ------------------------- workspace layout (bytes) ------------------------
static constexpr size_t SZ_WTQKV = (size_t)4 * 2304 * 768 * 2;
static constexpr size_t SZ_WTO   = (size_t)4 * 768 * 768 * 2;
static constexpr size_t SZ_WTI   = (size_t)4 * 3072 * 768 * 2;
static constexpr size_t SZ_WTF   = (size_t)4 * 768 * 3072 * 2;
static constexpr size_t SZ_BQKV  = (size_t)4 * 2304 * 4;
static constexpr size_t SZ_H32   = (size_t)8192 * 768 * 4;
static constexpr size_t SZ_HBF   = (size_t)8192 * 768 * 2;
static constexpr size_t SZ_QKV   = (size_t)8192 * 2304 * 2;
static constexpr size_t SZ_ATTN  = (size_t)8192 * 768 * 2;
static constexpr size_t SZ_TMP   = (size_t)8192 * 768 * 4;   // also holds Vt (12.6MB)

static constexpr size_t OFF_WTQKV = 0;
static constexpr size_t OFF_WTO   = OFF_WTQKV + SZ_WTQKV;
static constexpr size_t OFF_WTI   = OFF_WTO   + SZ_WTO;
static constexpr size_t OFF_WTF   = OFF_WTI   + SZ_WTI;
static constexpr size_t OFF_BQKV  = OFF_WTF   + SZ_WTF;
static constexpr size_t OFF_H32   = OFF_BQKV  + SZ_BQKV;
static constexpr size_t OFF_HBF   = OFF_H32   + SZ_H32;
static constexpr size_t OFF_QKV   = OFF_HBF   + SZ_HBF;
static constexpr size_t OFF_ATTN  = OFF_QKV   + SZ_QKV;
static constexpr size_t OFF_TMP   = OFF_ATTN  + SZ_ATTN;
static constexpr size_t OFF_FFN1  = OFF_TMP   + SZ_TMP;

// ------------------------- weight transpose + cast -------------------------
__global__ __launch_bounds__(256) void transpose_cast(
    const float* __restrict__ src, bf16* __restrict__ dst,
    int K, int N, long sStride, long dStride) {
  __shared__ float tile[32][33];
  const int l = blockIdx.z;
  src += (long)l * sStride;
  dst += (long)l * dStride;
  const int n0 = blockIdx.x * 32, k0 = blockIdx.y * 32;
  const int tx = threadIdx.x, ty = threadIdx.y; // (32,8)
#pragma unroll
  for (int i = 0; i < 4; ++i)
    tile[ty + i * 8][tx] = src[(long)(k0 + ty + i * 8) * N + n0 + tx];
  __syncthreads();
#pragma unroll
  for (int i = 0; i < 4; ++i)
    dst[(long)(n0 + ty + i * 8) * K + k0 + tx] = (bf16)tile[tx][ty + i * 8];
}

__global__ void bias_concat(const float* __restrict__ bq, const float* __restrict__ bk,
                            const float* __restrict__ bv, float* __restrict__ bqkv) {
  int i = blockIdx.x * 256 + threadIdx.x; // 4*2304
  if (i >= 4 * 2304) return;
  int l = i / 2304, p = i % 2304;
  float v = (p < 768) ? bq[l * 768 + p]
          : (p < 1536) ? bk[l * 768 + p - 768] : bv[l * 768 + p - 1536];
  bqkv[i] = v;
}

// ------------------------------ LN helpers ---------------------------------
__device__ __forceinline__ void block_stats(float s1, float s2, float* red,
                                            float& mean, float& inv) {
  const int lane = threadIdx.x & 63, wave = threadIdx.x >> 6;
#pragma unroll
  for (int off = 32; off > 0; off >>= 1) {
    s1 += __shfl_down(s1, off, 64);
    s2 += __shfl_down(s2, off, 64);
  }
  if (lane == 0) { red[wave] = s1; red[4 + wave] = s2; }
  __syncthreads();
  s1 = red[0] + red[1] + red[2] + red[3];
  s2 = red[4] + red[5] + red[6] + red[7];
  mean = s1 * (1.f / 768.f);
  float var = s2 * (1.f / 768.f) - mean * mean;
  inv = rsqrtf(var + 1e-12f);
}

__global__ __launch_bounds__(256) void embed_ln_kernel(
    const float* __restrict__ emb, const float* __restrict__ pos,
    const float* __restrict__ tok, const float* __restrict__ g,
    const float* __restrict__ bta, float* __restrict__ h32, bf16* __restrict__ hbf) {
  __shared__ float red[8];
  const long base = (long)blockIdx.x * 768;
  const int s = blockIdx.x & 4095;
  const int t = threadIdx.x;
  float x[3], s1 = 0.f, s2 = 0.f;
#pragma unroll
  for (int i = 0; i < 3; ++i) {
    int c = t + i * 256;
    float v = emb[base + c] + pos[(long)(s + 1) * 768 + c] + tok[c];
    x[i] = v; s1 += v; s2 += v * v;
  }
  float mean, inv;
  block_stats(s1, s2, red, mean, inv);
#pragma unroll
  for (int i = 0; i < 3; ++i) {
    int c = t + i * 256;
    float y = (x[i] - mean) * inv * g[c] + bta[c];
    h32[base + c] = y;
    hbf[base + c] = (bf16)y;
  }
}

// h = LN(h32 + p0 + p1 + bias); p0/p1 are bf16 split-K partials.
__global__ __launch_bounds__(256) void add_ln_kernel(
    float* __restrict__ h32, const bf16* __restrict__ p0,
    const bf16* __restrict__ p1, const float* __restrict__ bias,
    const float* __restrict__ g, const float* __restrict__ bta,
    bf16* __restrict__ hbf) {
  __shared__ float red[8];
  const long base = (long)blockIdx.x * 768;
  const int t = threadIdx.x;
  float x[3], s1 = 0.f, s2 = 0.f;
#pragma unroll
  for (int i = 0; i < 3; ++i) {
    int c = t + i * 256;
    float v = h32[base + c] + (float)p0[base + c] + (float)p1[base + c] + bias[c];
    x[i] = v; s1 += v; s2 += v * v;
  }
  float mean, inv;
  block_stats(s1, s2, red, mean, inv);
#pragma unroll
  for (int i = 0; i < 3; ++i) {
    int c = t + i * 256;
    float y = (x[i] - mean) * inv * g[c] + bta[c];
    h32[base + c] = y;
    hbf[base + c] = (bf16)y;
  }
}

// ------------------------------- GEMM --------------------------------------
// m-major grid (id%8 = x%8 -> one A-slab per XCD). Single-buffered 32KB k-loop
// + XOR swizzle (chunk ^= row&7). Coalesced epilogue: each wave stages its
// 16x64 output chunks into a private padded (stride-72) LDS slice of the dead
// As buffer, reads back row-contiguous bf16x8, stores 16B per lane.
// MODE: 0 = bf16 partial (split-K via z, no bias), 1 = bf16+bias, 2 = +GELU.
template <int MODE>
__global__ __launch_bounds__(256) void gemm_kernel(
    const bf16* __restrict__ A, const bf16* __restrict__ BT,
    const float* __restrict__ bias, void* __restrict__ C0, void* __restrict__ C1,
    int N, int ld, int ksize) {
  __shared__ bf16 As[128 * 64];
  __shared__ bf16 Bs[128 * 64];
  const int tid  = threadIdx.x;
  const int wave = tid >> 6, lane = tid & 63, l15 = lane & 15, quad = lane >> 4;
  const int wm = wave >> 1, wn = wave & 1;
  const long m0 = (long)blockIdx.x * 128;
  const int  n0 = blockIdx.y * 128;
  const int  k0 = blockIdx.z * ksize;

  floatx4 acc[4][4] = {};
  const bf16* Ag = A + m0 * ld + k0;
  const bf16* Bg = BT + (long)n0 * ld + k0;
  const int rowoff = tid >> 3;
  const int sc_sw = (tid & 7) ^ (rowoff & 7);   // swizzled global chunk
  const int fsw = l15 & 7;                       // frag-read swizzle key

  for (int kt = 0; kt < ksize; kt += 64) {
#pragma unroll
    for (int p = 0; p < 4; ++p) {
      const int row = p * 32 + rowoff;
      gld_lds16(Ag + (long)row * ld + kt + sc_sw * 8, As + p * 2048 + wave * 512);
      gld_lds16(Bg + (long)row * ld + kt + sc_sw * 8, Bs + p * 2048 + wave * 512);
    }
    __syncthreads();
#pragma unroll
    for (int kk = 0; kk < 2; ++kk) {
      const int ch = ((kk * 4 + quad) ^ fsw) * 8;  // swizzled chunk offset
      bf16x8 af[4], bfr[4];
#pragma unroll
      for (int mt = 0; mt < 4; ++mt)
        af[mt] = *(const bf16x8*)&As[(wm * 64 + mt * 16 + l15) * 64 + ch];
#pragma unroll
      for (int nt = 0; nt < 4; ++nt)
        bfr[nt] = *(const bf16x8*)&Bs[(wn * 64 + nt * 16 + l15) * 64 + ch];
#pragma unroll
      for (int mt = 0; mt < 4; ++mt)
#pragma unroll
        for (int nt = 0; nt < 4; ++nt)
          acc[mt][nt] = MFMA16(af[mt], bfr[nt], acc[mt][nt]);
    }
    __syncthreads();
  }

  // ---- coalesced epilogue (wave-private LDS slice; As is dead) ----
  bf16* Cg = (bf16*)((MODE == 0 && blockIdx.z != 0) ? C1 : C0);
  bf16* Es = As + wave * 1152;              // 16 rows x 72 (padded) per wave
#pragma unroll
  for (int mt = 0; mt < 4; ++mt) {
#pragma unroll
    for (int nt = 0; nt < 4; ++nt) {
      const float bb = (MODE == 0) ? 0.f : bias[n0 + wn * 64 + nt * 16 + l15];
#pragma unroll
      for (int r = 0; r < 4; ++r) {
        float v = acc[mt][nt][r] + bb;
        if (MODE == 2) v = gelu_tanh(v);
        Es[(quad * 4 + r) * 72 + nt * 16 + l15] = (bf16)v;
      }
    }
    // wave-internal: lockstep, compiler inserts lgkmcnt waits
#pragma unroll
    for (int p = 0; p < 2; ++p) {
      const int rr = p * 8 + (lane >> 3);
      const int cc = (lane & 7) * 8;
      bf16x8 vv = *(const bf16x8*)&Es[rr * 72 + cc];
      *(bf16x8*)&Cg[(m0 + wm * 64 + mt * 16 + rr) * N + n0 + wn * 64 + cc] = vv;
    }
  }
}

// -------------------- V transpose: qkv V-part -> Vt[b,h][d][S] -------------
__global__ __launch_bounds__(256) void vtrans_kernel(
    const bf16* __restrict__ qkv, bf16* __restrict__ vt) {
  __shared__ bf16 tile[64 * 68];
  const int s0 = blockIdx.x * 64, h = blockIdx.y, b = blockIdx.z;
  const int tid = threadIdx.x;
  const bf16* src = qkv + (long)b * 4096 * 2304 + 1536 + h * 64;
#pragma unroll
  for (int p = 0; p < 2; ++p) {
    const int i = p * 256 + tid;
    const int r = i >> 3, c = i & 7;
    *(uint4*)&tile[r * 68 + c * 8] = *(const uint4*)&src[(long)(s0 + r) * 2304 + c * 8];
  }
  __syncthreads();
  bf16* dst = vt + ((long)(b * 12 + h)) * 64 * 4096;
#pragma unroll
  for (int p = 0; p < 2; ++p) {
    const int i = p * 256 + tid;
    const int d = i >> 3, cs = i & 7;
    bf16 vals[8];
#pragma unroll
    for (int u = 0; u < 8; ++u) vals[u] = tile[(cs * 8 + u) * 68 + d];
    *(uint4*)&dst[(long)d * 4096 + s0 + cs * 8] = *(const uint4*)vals;
  }
}

// ----------------------------- attention -----------------------------------
__global__ __launch_bounds__(256) void attn_kernel(
    const bf16* __restrict__ qkv, const bf16* __restrict__ vt,
    const int* __restrict__ amask, bf16* __restrict__ attn_out) {
  constexpr int S = 4096, HID3 = 2304;
  __shared__ bf16 Ss[64 * 328];
  __shared__ bf16 Ts[64 * 64];
  __shared__ float redm[64], reds[64];

  const int x = blockIdx.x, q0 = x * 64, h = blockIdx.y, b = blockIdx.z;
  const int tid = threadIdx.x, wave = tid >> 6, lane = tid & 63;
  const int l15 = lane & 15, quad = lane >> 4;
  const int rowoff = tid >> 3;
  const int sc_sw = (tid & 7) ^ (rowoff & 7);
  const int fsw = l15 & 7;
  const int t_lo = (x < 2) ? (2 - x) : 0;
  const int t_hi = (x > 61) ? (66 - x) : 5;

  const bf16* Qb = qkv + (long)b * S * HID3 + h * 64;
  const bf16* Kb = Qb + 768;
  const bf16* Vt_bh = vt + ((long)(b * 12 + h)) * 64 * 4096;

  bf16x8 qf[2];
  {
    const long qrow = q0 + wave * 16 + l15;
    qf[0] = *(const bf16x8*)&Qb[qrow * HID3 + quad * 8];
    qf[1] = *(const bf16x8*)&Qb[qrow * HID3 + 32 + quad * 8];
  }

  float mrow[4] = {-3e38f, -3e38f, -3e38f, -3e38f};

  // ---- Phase A: scores ----
  for (int t = t_lo; t < t_hi; ++t) {
    const int j0 = (x - 2 + t) * 64;
    __syncthreads();
#pragma unroll
    for (int p = 0; p < 2; ++p) {
      const int key = p * 32 + rowoff;
      gld_lds16(Kb + (long)(j0 + key) * HID3 + sc_sw * 8, &Ts[p * 2048 + wave * 512]);
    }
    __syncthreads();
    floatx4 sacc[4] = {};
#pragma unroll
    for (int kk = 0; kk < 2; ++kk) {
      const int ch = ((kk * 4 + quad) ^ fsw) * 8;
#pragma unroll
      for (int nt = 0; nt < 4; ++nt) {
        bf16x8 kf = *(const bf16x8*)&Ts[(nt * 16 + l15) * 64 + ch];
        sacc[nt] = MFMA16(qf[kk], kf, sacc[nt]);
      }
    }
#pragma unroll
    for (int nt = 0; nt < 4; ++nt) {
      const int jj = t * 64 + nt * 16 + l15;
      const int j = j0 + nt * 16 + l15;
      const bool jv = (amask[b * S + j] != 0);
#pragma unroll
      for (int r = 0; r < 4; ++r) {
        const int qi = wave * 16 + quad * 4 + r;
        const bool ok = jv && (jj >= qi) && (jj <= qi + 256);
        const float sv = ok ? sacc[nt][r] * 0.125f : -1e9f;
        mrow[r] = fmaxf(mrow[r], sv);
        Ss[(wave * 16 + quad * 4 + r) * 328 + jj] = (bf16)sv;
      }
    }
  }
#pragma unroll
  for (int off = 1; off < 16; off <<= 1)
#pragma unroll
    for (int r = 0; r < 4; ++r)
      mrow[r] = fmaxf(mrow[r], __shfl_xor(mrow[r], off, 64));
  if (l15 == 0) {
#pragma unroll
    for (int r = 0; r < 4; ++r) redm[wave * 16 + quad * 4 + r] = mrow[r];
  }
  __syncthreads();

  // ---- Phase B: softmax pass (rows re-owned by l15, chunks by quad) ----
  {
    const int row = wave * 16 + l15;
    const float mx = redm[row];
    float sum = 0.f;
    for (int c = t_lo * 8 + quad; c < t_hi * 8; c += 4) {
      bf16x8 pv = *(const bf16x8*)&Ss[row * 328 + c * 8];
#pragma unroll
      for (int u = 0; u < 8; ++u) {
        const float p = __expf((float)pv[u] - mx);
        sum += p;
        pv[u] = (bf16)p;
      }
      *(bf16x8*)&Ss[row * 328 + c * 8] = pv;
    }
    sum += __shfl_xor(sum, 16, 64);
    sum += __shfl_xor(sum, 32, 64);
    if (quad == 0) reds[row] = sum;
  }
  __syncthreads();

  // ---- Phase C: P @ V with pre-transposed V ----
  floatx4 oacc[4] = {};
  for (int t = t_lo; t < t_hi; ++t) {
    const int j0 = (x - 2 + t) * 64;
    __syncthreads();
#pragma unroll
    for (int p = 0; p < 2; ++p) {
      const int d = p * 32 + rowoff;
      gld_lds16(Vt_bh + (long)d * 4096 + j0 + sc_sw * 8, &Ts[p * 2048 + wave * 512]);
    }
    __syncthreads();
#pragma unroll
    for (int kk = 0; kk < 2; ++kk) {
      const int ko = kk * 32 + quad * 8;
      const int ch = ((kk * 4 + quad) ^ fsw) * 8;
      bf16x8 pf = *(const bf16x8*)&Ss[(wave * 16 + l15) * 328 + t * 64 + ko];
#pragma unroll
      for (int nt = 0; nt < 4; ++nt) {
        bf16x8 vf = *(const bf16x8*)&Ts[(nt * 16 + l15) * 64 + ch];
        oacc[nt] = MFMA16(pf, vf, oacc[nt]);
      }
    }
  }

  float inv[4];
#pragma unroll
  for (int r = 0; r < 4; ++r) inv[r] = fast_rcp(reds[wave * 16 + quad * 4 + r]);
  const long orow = (long)b * S + q0 + wave * 16 + quad * 4;
#pragma unroll
  for (int nt = 0; nt < 4; ++nt)
#pragma unroll
    for (int r = 0; r < 4; ++r)
      attn_out[(orow + r) * 768 + h * 64 + nt * 16 + l15] =
          (bf16)(oacc[nt][r] * inv[r]);
}

// ------------------------------ final head ---------------------------------
__global__ __launch_bounds__(256) void final_kernel(
    const float* __restrict__ h32, const float* __restrict__ Wp,
    const float* __restrict__ bp, float* __restrict__ out) {
  const int wave = threadIdx.x >> 6, lane = threadIdx.x & 63;
  const long tok = (long)blockIdx.x * 4 + wave;
  float s = 0.f;
#pragma unroll
  for (int i = 0; i < 12; ++i) {
    const int c = lane + i * 64;
    s += h32[tok * 768 + c] * Wp[c];
  }
#pragma unroll
  for (int off = 32; off > 0; off >>= 1) s += __shfl_down(s, off, 64);
  if (lane == 0) out[tok] = fast_rcp(1.f + __expf(-(s + bp[0])));
}

// ------------------------------ launcher -----------------------------------
extern "C" void kernel_launch(void* const* d_in, const int* in_sizes, int n_in,
                              void* d_out, int out_size, void* d_ws, size_t ws_size,
                              hipStream_t stream) {
  const float* emb   = (const float*)d_in[0];
  const int*   amask = (const int*)d_in[1];
  const float* pos   = (const float*)d_in[2];
  const float* tok   = (const float*)d_in[3];
  const float* elng  = (const float*)d_in[4];
  const float* elnb  = (const float*)d_in[5];
  const float* Wq = (const float*)d_in[6];   const float* bq = (const float*)d_in[7];
  const float* Wk = (const float*)d_in[8];   const float* bk = (const float*)d_in[9];
  const float* Wv = (const float*)d_in[10];  const float* bv = (const float*)d_in[11];
  const float* Wo = (const float*)d_in[12];  const float* bo = (const float*)d_in[13];
  const float* ln1g = (const float*)d_in[14]; const float* ln1b = (const float*)d_in[15];
  const float* Wi = (const float*)d_in[16];  const float* bi = (const float*)d_in[17];
  const float* Wf = (const float*)d_in[18];  const float* bfb = (const float*)d_in[19];
  const float* ln2g = (const float*)d_in[20]; const float* ln2b = (const float*)d_in[21];
  const float* Wp = (const float*)d_in[22];  const float* bp = (const float*)d_in[23];
  float* out = (float*)d_out;

  char* ws = (char*)d_ws;
  bf16*  WTqkv = (bf16*)(ws + OFF_WTQKV);
  bf16*  WTo   = (bf16*)(ws + OFF_WTO);
  bf16*  WTi   = (bf16*)(ws + OFF_WTI);
  bf16*  WTf   = (bf16*)(ws + OFF_WTF);
  float* bqkv  = (float*)(ws + OFF_BQKV);
  float* h32   = (float*)(ws + OFF_H32);
  bf16*  hbf   = (bf16*)(ws + OFF_HBF);
  bf16*  qkvb  = (bf16*)(ws + OFF_QKV);
  bf16*  part1 = (bf16*)(ws + OFF_QKV);    // bf16 overlay; qkvb dead after attn
  bf16*  attnb = (bf16*)(ws + OFF_ATTN);
  bf16*  part0 = (bf16*)(ws + OFF_TMP);
  bf16*  vtb   = (bf16*)(ws + OFF_TMP);    // Vt overlay; part0 dead during attn
  bf16*  ffn1  = (bf16*)(ws + OFF_FFN1);

  const dim3 tb(32, 8, 1);
  transpose_cast<<<dim3(24, 24, 4), tb, 0, stream>>>(Wq, WTqkv,               768, 768,  (long)768 * 768,  (long)2304 * 768);
  transpose_cast<<<dim3(24, 24, 4), tb, 0, stream>>>(Wk, WTqkv + 768 * 768,   768, 768,  (long)768 * 768,  (long)2304 * 768);
  transpose_cast<<<dim3(24, 24, 4), tb, 0, stream>>>(Wv, WTqkv + 1536 * 768,  768, 768,  (long)768 * 768,  (long)2304 * 768);
  transpose_cast<<<dim3(24, 24, 4), tb, 0, stream>>>(Wo, WTo,                 768, 768,  (long)768 * 768,  (long)768 * 768);
  transpose_cast<<<dim3(96, 24, 4), tb, 0, stream>>>(Wi, WTi,                 768, 3072, (long)768 * 3072, (long)3072 * 768);
  transpose_cast<<<dim3(24, 96, 4), tb, 0, stream>>>(Wf, WTf,                 3072, 768, (long)3072 * 768, (long)768 * 3072);
  bias_concat<<<36, 256, 0, stream>>>(bq, bk, bv, bqkv);

  embed_ln_kernel<<<8192, 256, 0, stream>>>(emb, pos, tok, elng, elnb, h32, hbf);

  for (int l = 0; l < 4; ++l) {
    gemm_kernel<1><<<dim3(64, 18, 1), 256, 0, stream>>>(
        hbf, WTqkv + (size_t)l * 2304 * 768, bqkv + l * 2304, qkvb, nullptr, 2304, 768, 768);
    vtrans_kernel<<<dim3(64, 12, 2), 256, 0, stream>>>(qkvb, vtb);
    attn_kernel<<<dim3(64, 12, 2), 256, 0, stream>>>(qkvb, vtb, amask, attnb);
    gemm_kernel<0><<<dim3(64, 6, 2), 256, 0, stream>>>(
        attnb, WTo + (size_t)l * 768 * 768, nullptr, part0, part1, 768, 768, 384);
    add_ln_kernel<<<8192, 256, 0, stream>>>(h32, part0, part1, bo + l * 768,
                                            ln1g + l * 768, ln1b + l * 768, hbf);
    gemm_kernel<2><<<dim3(64, 24, 1), 256, 0, stream>>>(
        hbf, WTi + (size_t)l * 3072 * 768, bi + l * 3072, ffn1, nullptr, 3072, 768, 768);
    gemm_kernel<0><<<dim3(64, 6, 2), 256, 0, stream>>>(
        ffn1, WTf + (size_t)l * 768 * 3072, nullptr, part0, part1, 768, 3072, 1536);
    add_ln_kernel<<<8192, 256, 0, stream>>>(h32, part0, part1, bfb + l * 768,
                                            ln2g + l * 768, ln2b + l * 768, hbf);
  }

  final_kernel<<<2048, 256, 0, stream>>>(h32, Wp, bp, out);
}